// Round 8
// baseline (57004.077 us; speedup 1.0000x reference)
//
#include <hip/hip_runtime.h>
#include <math.h>

// ---------------------------------------------------------------------------
// LSTM_FEAT_2: T=4096 sequential 2-layer LSTM + log-softmax feedback.
// R8: R7's verified compute structure (256wg x 512thr, 1 wg/CU forced by
// 133KB LDS, weights reg+LDS resident, VGPR=108 no spill) with the sync
// fabric replaced: counter-tree barriers + y-counter (3-4 LLC RTs each,
// RMW-contended lines) -> seq-valued per-wg FLAGS, no atomics anywhere.
//   producer: frag stores -> vmcnt(0) -> flag[wid]=t+1  (plain agent store)
//   consumer: wave0 lanes check 4 flags each via two 8B loads = all 256
//             flags in ONE round-trip per poll iteration.
// A polls only flags_h2 (h1 condition implied by B(t-1)'s poll); B polls
// only flags_h1. Drift <1 step => double buffers provably safe.
//
// Math (unchanged, verified R7):
//   feat_t = Ws@x_t + bs                       (startup kernel)
//   Wih1e@embed = WCL@h2 + biasE2 - rsWC*lse,  WCL=(Wih1e@Wm)@Wl
//   gates1 = [Wih1s|Whh1]@[feat;h1] + WCL@h2 + biasA [+ biasE2 - rsWC*lse]
//   gates2 = [Wih2|Whh2]@[h1;h2] + biasB
//   y_t    = Wl@h2_t + bl -> d_out ; post-pass: out = log_softmax(out)
// ---------------------------------------------------------------------------

#define T_STEPS 4096
#define NWG 256

// ws layout (bytes)
#define WS_FH1   0            // 256 u32 flags: h1 ready (value = steps done)
#define WS_FH2   4096         // 256 u32 flags: h2 ready
#define WS_FY    8192         // 256 u32 flags: y row published
#define WS_H1    12288        // float[2][1024]
#define WS_H2    20480        // float[2][1024]
#define WS_ZERO_BYTES 28672
#define WS_FEAT  28672        // float[4096][512] -> end ~8.4MB

// dynamic LDS partition (floats)
#define OFF_WA 2560           // s_in[2560] | wa[16][1024] | wb[16][768] | wy[2][1024]
#define OFF_WB 18944
#define OFF_WY 31232
#define SMEM_FLOATS 33280
#define SMEM_BYTES  (SMEM_FLOATS*4)

#define PIN4(v) asm volatile("" : "+v"((v).x), "+v"((v).y), "+v"((v).z), "+v"((v).w))
#define PIN1(v) asm volatile("" : "+v"(v))
#define FMA4(acc,s,v4) {(acc).x += (s)*(v4).x; (acc).y += (s)*(v4).y; (acc).z += (s)*(v4).z; (acc).w += (s)*(v4).w;}
#define DOT4(a,b) ((a).x*(b).x + (a).y*(b).y + (a).z*(b).z + (a).w*(b).w)

__device__ __forceinline__ float AL(const float* p){
  return __hip_atomic_load(p, __ATOMIC_RELAXED, __HIP_MEMORY_SCOPE_AGENT);
}
__device__ __forceinline__ float2 AL2(const float* p){
  unsigned long long u = __hip_atomic_load((const unsigned long long*)p,
                                           __ATOMIC_RELAXED, __HIP_MEMORY_SCOPE_AGENT);
  union { unsigned long long u; float2 f; } c; c.u = u; return c.f;
}
__device__ __forceinline__ void AS(float* p, float v){
  __hip_atomic_store(p, v, __ATOMIC_RELAXED, __HIP_MEMORY_SCOPE_AGENT);
}
__device__ __forceinline__ void AS32(unsigned* p, unsigned v){
  __hip_atomic_store(p, v, __ATOMIC_RELAXED, __HIP_MEMORY_SCOPE_AGENT);
}
__device__ __forceinline__ float sigm(float x){ return 1.0f/(1.0f+expf(-x)); }

// wave0-lane poll: lane l guards flags[4l..4l+3]; exits when all >= need.
__device__ __forceinline__ void poll4(const unsigned* flags, unsigned need){
  const int l = threadIdx.x & 63;
  const unsigned long long* p = (const unsigned long long*)(flags + 4*l);
  for(;;){
    unsigned long long a = __hip_atomic_load(p,     __ATOMIC_RELAXED, __HIP_MEMORY_SCOPE_AGENT);
    unsigned long long b = __hip_atomic_load(p + 1, __ATOMIC_RELAXED, __HIP_MEMORY_SCOPE_AGENT);
    if ((unsigned)a >= need && (unsigned)(a >> 32) >= need &&
        (unsigned)b >= need && (unsigned)(b >> 32) >= need) return;
    __builtin_amdgcn_s_sleep(1);
  }
}

// ---------------------------------------------------------------------------
// startup: feat[t][k] = Ws[k]·x[t] + bs[k]
__global__ __launch_bounds__(512) void feat_kernel(
    const float* __restrict__ x, const float* __restrict__ Ws,
    const float* __restrict__ bs, float* __restrict__ feat)
{
  __shared__ float s_x[16][360];
  __shared__ float s_w[512][20];
  const int bid = blockIdx.x, tid = threadIdx.x;
  const int t0 = bid * 16;
  for (int tt = 0; tt < 16; tt++)
    if (tid < 360) s_x[tt][tid] = x[(t0+tt)*360 + tid];
  float acc[16];
  #pragma unroll
  for (int i = 0; i < 16; i++) acc[i] = 0.f;
  for (int d0 = 0; d0 < 360; d0 += 16){
    const int dn = (360 - d0 < 16) ? (360 - d0) : 16;
    __syncthreads();
    if (dn == 16){
      #pragma unroll
      for (int c4 = 0; c4 < 4; c4++)
        *(float4*)&s_w[tid][c4*4] = *(const float4*)&Ws[tid*360 + d0 + c4*4];
    } else {
      for (int c = 0; c < dn; c++) s_w[tid][c] = Ws[tid*360 + d0 + c];
    }
    __syncthreads();
    for (int c = 0; c < dn; c++){
      float wv = s_w[tid][c];
      #pragma unroll
      for (int tt = 0; tt < 16; tt++) acc[tt] += wv * s_x[tt][d0 + c];
    }
  }
  for (int tt = 0; tt < 16; tt++)
    feat[(t0+tt)*512 + tid] = acc[tt] + bs[tid];
}

// ---------------------------------------------------------------------------
// post-pass: out[t] = out[t] - logsumexp(out[t])  (in place)
__global__ __launch_bounds__(64) void ls_kernel(float* __restrict__ out)
{
  const int t = blockIdx.x, l = threadIdx.x;
  float v[8];
  #pragma unroll
  for (int i = 0; i < 8; i++) v[i] = out[t*512 + l*8 + i];
  float m0 = v[0];
  #pragma unroll
  for (int i = 1; i < 8; i++) m0 = fmaxf(m0, v[i]);
  #pragma unroll
  for (int mk = 32; mk; mk >>= 1) m0 = fmaxf(m0, __shfl_xor(m0, mk));
  float s = 0.f;
  #pragma unroll
  for (int i = 0; i < 8; i++) s += expf(v[i] - m0);
  #pragma unroll
  for (int mk = 32; mk; mk >>= 1) s += __shfl_xor(s, mk);
  float lse = m0 + logf(s);
  #pragma unroll
  for (int i = 0; i < 8; i++) out[t*512 + l*8 + i] = v[i] - lse;
}

// ---------------------------------------------------------------------------
// persistent kernel: 256 wgs x 512 thr (8 waves). Wave w owns gate rows
// {2w, 2w+1}; lane l owns f4 col-chunks at dword 256*j + 4*l (bank-clean).
__global__ __launch_bounds__(512, 1) void lstm_persist(
    const float* __restrict__ Wih1, const float* __restrict__ Whh1,
    const float* __restrict__ Wih2, const float* __restrict__ Whh2,
    const float* __restrict__ Wl,   const float* __restrict__ Wm,
    const float* __restrict__ bih1, const float* __restrict__ bhh1,
    const float* __restrict__ bih2, const float* __restrict__ bhh2,
    const float* __restrict__ blp,  const float* __restrict__ bmp,
    char* __restrict__ wsb, float* __restrict__ out)
{
  extern __shared__ float smem[];
  float* s_in = smem;               // 2560: A: [feat|h1|h2]; B restages h1 only
  float* wa   = smem + OFF_WA;      // [16][1024] = WCL rows
  float* wb   = smem + OFF_WB;      // [16][768]  = Whh2 cols 256..1023 (init: WCtmp)
  float* wy   = smem + OFF_WY;      // [2][1024]  = Wl rows wid*2, wid*2+1
  __shared__ float s_part[16];
  __shared__ float s_py[8];
  __shared__ float s_sums[32];

  unsigned* fh1 = (unsigned*)(wsb + WS_FH1);
  unsigned* fh2 = (unsigned*)(wsb + WS_FH2);
  unsigned* fy  = (unsigned*)(wsb + WS_FY);
  float* h1b = (float*)(wsb + WS_H1);
  float* h2b = (float*)(wsb + WS_H2);
  const float* featp = (const float*)(wsb + WS_FEAT);

  const int wid = blockIdx.x, tid = threadIdx.x;
  const int w = tid >> 6, l = tid & 63;
  const int o0 = 2*w, o1 = 2*w + 1;
  const int rA0 = (o0 >> 2)*1024 + wid*4 + (o0 & 3);
  const int rA1 = (o1 >> 2)*1024 + wid*4 + (o1 & 3);

  // ===== init 1: stage this wg's 16 Wih1e rows (16x128) into s_in =====
  for (int idx = tid; idx < 2048; idx += 512){
    int o = idx >> 7, e = idx & 127;
    int r = (o >> 2)*1024 + wid*4 + (o & 3);
    s_in[idx] = Wih1[r*640 + 512 + e];
  }
  __syncthreads();

  // ===== init 2: WCtmp = Wih1e @ Wm  (16x512) -> wb area =====
  {
    float4 a00 = {0,0,0,0}, a01 = a00, a10 = a00, a11 = a00;
    for (int e = 0; e < 128; e++){
      float w0e = s_in[o0*128 + e], w1e = s_in[o1*128 + e];
      float4 m0 = *(const float4*)&Wm[e*512 + l*4];
      float4 m1 = *(const float4*)&Wm[e*512 + l*4 + 256];
      FMA4(a00, w0e, m0); FMA4(a01, w0e, m1);
      FMA4(a10, w1e, m0); FMA4(a11, w1e, m1);
    }
    *(float4*)&wb[o0*512 + l*4]       = a00;
    *(float4*)&wb[o0*512 + l*4 + 256] = a01;
    *(float4*)&wb[o1*512 + l*4]       = a10;
    *(float4*)&wb[o1*512 + l*4 + 256] = a11;
  }
  __syncthreads();

  // ===== init 3: WCL = WCtmp @ Wl (16x1024) -> wa; rowsum/bl piggyback =====
  {
    float4 c00={0,0,0,0}, c01=c00, c02=c00, c03=c00;
    float4 c10=c00, c11=c00, c12=c00, c13=c00;
    float rs0=0.f, rs1=0.f, wl0=0.f, wl1=0.f;
    for (int m = 0; m < 512; m++){
      float t0 = wb[o0*512 + m], t1 = wb[o1*512 + m];
      float blm = blp[m];
      rs0 += t0; wl0 += t0*blm; rs1 += t1; wl1 += t1*blm;
      float4 q0 = *(const float4*)&Wl[m*1024 + l*4];
      float4 q1 = *(const float4*)&Wl[m*1024 + l*4 + 256];
      float4 q2 = *(const float4*)&Wl[m*1024 + l*4 + 512];
      float4 q3 = *(const float4*)&Wl[m*1024 + l*4 + 768];
      FMA4(c00,t0,q0); FMA4(c01,t0,q1); FMA4(c02,t0,q2); FMA4(c03,t0,q3);
      FMA4(c10,t1,q0); FMA4(c11,t1,q1); FMA4(c12,t1,q2); FMA4(c13,t1,q3);
    }
    *(float4*)&wa[o0*1024 + l*4      ] = c00;
    *(float4*)&wa[o0*1024 + l*4 + 256] = c01;
    *(float4*)&wa[o0*1024 + l*4 + 512] = c02;
    *(float4*)&wa[o0*1024 + l*4 + 768] = c03;
    *(float4*)&wa[o1*1024 + l*4      ] = c10;
    *(float4*)&wa[o1*1024 + l*4 + 256] = c11;
    *(float4*)&wa[o1*1024 + l*4 + 512] = c12;
    *(float4*)&wa[o1*1024 + l*4 + 768] = c13;
    if (l == 0){
      s_sums[w*4+0] = rs0; s_sums[w*4+1] = rs1;
      s_sums[w*4+2] = wl0; s_sums[w*4+3] = wl1;
    }
  }
  __syncthreads();

  // ===== init 4: per-row bias regs (wave 0) =====
  float biasAreg=0.f, biasBreg=0.f, bE2reg=0.f, rsReg=0.f;
  float bl0=0.f, bl1=0.f, c1=0.f, c2=0.f;
  if (w == 0 && l < 16){
    int r = (l >> 2)*1024 + wid*4 + (l & 3);
    biasAreg = bih1[r] + bhh1[r];
    biasBreg = bih2[r] + bhh2[r];
    rsReg = s_sums[(l>>1)*4 + (l&1)];
    float acc = s_sums[(l>>1)*4 + 2 + (l&1)];
    for (int e = 0; e < 128; e++) acc += s_in[l*128 + e] * bmp[e];
    bE2reg = acc;
  }
  if (w == 0 && l == 0){ bl0 = blp[wid*2]; bl1 = blp[wid*2 + 1]; }

  // ===== init 5: LDS weights wb (Whh2 cols 256..1023) and wy (Wl rows) =====
  for (int o = 0; o < 16; o++){
    int r = (o >> 2)*1024 + wid*4 + (o & 3);
    for (int c = tid; c < 768; c += 512)
      wb[o*768 + c] = Whh2[r*1024 + 256 + c];
  }
  for (int idx = tid; idx < 2048; idx += 512){
    int row = idx >> 10, c = idx & 1023;
    wy[idx] = Wl[(wid*2 + row)*1024 + c];
  }

  // ===== init 6: pinned register weights (88 floats/thread) =====
  float4 wA0[6], wA1[6], wB0[5], wB1[5];
  #pragma unroll
  for (int j = 0; j < 6; j++){
    int c = 256*j + l*4;
    wA0[j] = (c < 512) ? *(const float4*)&Wih1[rA0*640 + c]
                       : *(const float4*)&Whh1[rA0*1024 + c - 512];
    wA1[j] = (c < 512) ? *(const float4*)&Wih1[rA1*640 + c]
                       : *(const float4*)&Whh1[rA1*1024 + c - 512];
  }
  #pragma unroll
  for (int j = 0; j < 5; j++){
    int c = 256*j + l*4;
    wB0[j] = (c < 1024) ? *(const float4*)&Wih2[rA0*1024 + c]
                        : *(const float4*)&Whh2[rA0*1024 + c - 1024];
    wB1[j] = (c < 1024) ? *(const float4*)&Wih2[rA1*1024 + c]
                        : *(const float4*)&Whh2[rA1*1024 + c - 1024];
  }
  #pragma unroll
  for (int j = 0; j < 6; j++){ PIN4(wA0[j]); PIN4(wA1[j]); }
  #pragma unroll
  for (int j = 0; j < 5; j++){ PIN4(wB0[j]); PIN4(wB1[j]); }
  PIN1(biasAreg); PIN1(biasBreg); PIN1(bE2reg); PIN1(rsReg);
  PIN1(bl0); PIN1(bl1);
  __syncthreads();

  // ===== main loop =====
  for (int t = 0; t < T_STEPS; t++){
    const int rb = t & 1, wbuf = (t + 1) & 1;

    // ---- A gate: wait for h2(t-1) from all wgs (h1 implied by B(t-1)) ----
    if (w == 0 && t > 0) poll4(fh2, (unsigned)t);
    __syncthreads();

    // ---- phase A stage: s_in = [feat(512) | h1(1024) | h2(1024)] ----
    {
      int s1 = tid*2;
      float2 v1 = (s1 < 512) ? *(const float2*)&featp[t*512 + s1]
                             : AL2(&h1b[rb*1024 + s1 - 512]);
      *(float2*)&s_in[s1] = v1;
      int s2 = 1024 + tid*2;
      float2 v2 = (tid < 256) ? AL2(&h1b[rb*1024 + s2 - 512])
                              : AL2(&h2b[rb*1024 + s2 - 1536]);
      *(float2*)&s_in[s2] = v2;
      if (tid < 256)
        *(float2*)&s_in[2048 + tid*2] = AL2(&h2b[rb*1024 + 512 + tid*2]);
    }
    __syncthreads();

    // ---- y(t-1) rows (overlap): waves 0-3 row wid*2, waves 4-7 row wid*2+1
    if (t > 0){
      int yrow = w >> 2, cb = (w & 3)*256 + l*4;
      float4 xv = *(float4*)&s_in[1536 + cb];
      float4 wv = *(float4*)&wy[yrow*1024 + cb];
      float yp = DOT4(wv, xv);
      #pragma unroll
      for (int mk = 32; mk; mk >>= 1) yp += __shfl_xor(yp, mk);
      if (l == 0) s_py[w] = yp;
    }
    __syncthreads();
    if (t > 0 && w == 0 && l == 0){
      float y0 = s_py[0]+s_py[1]+s_py[2]+s_py[3] + bl0;
      float y1 = s_py[4]+s_py[5]+s_py[6]+s_py[7] + bl1;
      AS(&out[(t-1)*512 + wid*2    ], y0);
      AS(&out[(t-1)*512 + wid*2 + 1], y1);
      asm volatile("s_waitcnt vmcnt(0)" ::: "memory");
      AS32(&fy[wid], (unsigned)t);
    }

    // ---- gates1 dot: regs j=0..5 (feat|h1) + LDS k=0..3 (WCL @ h2) ----
    float acc0 = 0.f, acc1 = 0.f;
    #pragma unroll
    for (int j = 0; j < 6; j++){
      float4 xv = *(float4*)&s_in[256*j + l*4];
      acc0 += DOT4(wA0[j], xv); acc1 += DOT4(wA1[j], xv);
    }
    #pragma unroll
    for (int k = 0; k < 4; k++){
      float4 xv = *(float4*)&s_in[1536 + 256*k + l*4];
      float4 u0 = *(float4*)&wa[o0*1024 + 256*k + l*4];
      float4 u1 = *(float4*)&wa[o1*1024 + 256*k + l*4];
      acc0 += DOT4(u0, xv); acc1 += DOT4(u1, xv);
    }
    #pragma unroll
    for (int mk = 32; mk; mk >>= 1){
      acc0 += __shfl_xor(acc0, mk); acc1 += __shfl_xor(acc1, mk);
    }
    if (l == 0){ s_part[o0] = acc0; s_part[o1] = acc1; }
    __syncthreads();

    // ---- lse(t-1): wave 0 polls y flags then gathers 512 y values ----
    float lse = 0.f;
    if (w == 0 && t > 0){
      poll4(fy, (unsigned)t);
      const float* yrow = &out[(t-1)*512];
      float v0 = AL(&yrow[l*8+0]), v1 = AL(&yrow[l*8+1]);
      float v2 = AL(&yrow[l*8+2]), v3 = AL(&yrow[l*8+3]);
      float v4 = AL(&yrow[l*8+4]), v5 = AL(&yrow[l*8+5]);
      float v6 = AL(&yrow[l*8+6]), v7 = AL(&yrow[l*8+7]);
      float m0 = fmaxf(fmaxf(fmaxf(v0,v1), fmaxf(v2,v3)),
                       fmaxf(fmaxf(v4,v5), fmaxf(v6,v7)));
      #pragma unroll
      for (int mk = 32; mk; mk >>= 1) m0 = fmaxf(m0, __shfl_xor(m0, mk));
      float s = expf(v0-m0)+expf(v1-m0)+expf(v2-m0)+expf(v3-m0)
              + expf(v4-m0)+expf(v5-m0)+expf(v6-m0)+expf(v7-m0);
      #pragma unroll
      for (int mk = 32; mk; mk >>= 1) s += __shfl_xor(s, mk);
      lse = m0 + logf(s);
    }
    if (w == 0 && l < 16){
      float sum = s_part[l] + biasAreg;
      if (t > 0) sum += bE2reg - rsReg*lse;
      float gi = __shfl(sum, (l & 3));
      float gf = __shfl(sum, 4 + (l & 3));
      float gg = __shfl(sum, 8 + (l & 3));
      float go = __shfl(sum, 12 + (l & 3));
      if (l < 4){
        float cn = sigm(gf)*c1 + sigm(gi)*tanhf(gg);
        c1 = cn;
        AS(&h1b[wbuf*1024 + wid*4 + l], sigm(go)*tanhf(cn));
      }
    }
    __syncthreads();                       // drains all lanes' h1 stores
    if (tid == 0){
      asm volatile("s_waitcnt vmcnt(0)" ::: "memory");
      AS32(&fh1[wid], (unsigned)(t + 1));
    }

    // ---- B gate: wait for h1(t) from all wgs ----
    if (w == 0) poll4(fh1, (unsigned)(t + 1));
    __syncthreads();

    // ---- phase B stage: restage h1 only; h2(t-1) kept in s_in[1536..2560)
    *(float2*)&s_in[tid*2] = AL2(&h1b[wbuf*1024 + tid*2]);
    __syncthreads();

    // ---- gates2 dot: regs j=0..3 (h1) + j=4 (h2[0..255]) + LDS k=0..2 ----
    float b0 = 0.f, b1 = 0.f;
    #pragma unroll
    for (int j = 0; j < 4; j++){
      float4 xv = *(float4*)&s_in[256*j + l*4];
      b0 += DOT4(wB0[j], xv); b1 += DOT4(wB1[j], xv);
    }
    {
      float4 xv = *(float4*)&s_in[1536 + l*4];
      b0 += DOT4(wB0[4], xv); b1 += DOT4(wB1[4], xv);
    }
    #pragma unroll
    for (int k = 0; k < 3; k++){
      float4 xv = *(float4*)&s_in[1536 + 256 + 256*k + l*4];
      float4 u0 = *(float4*)&wb[o0*768 + 256*k + l*4];
      float4 u1 = *(float4*)&wb[o1*768 + 256*k + l*4];
      b0 += DOT4(u0, xv); b1 += DOT4(u1, xv);
    }
    #pragma unroll
    for (int mk = 32; mk; mk >>= 1){
      b0 += __shfl_xor(b0, mk); b1 += __shfl_xor(b1, mk);
    }
    if (l == 0){ s_part[o0] = b0; s_part[o1] = b1; }
    __syncthreads();
    if (w == 0 && l < 16){
      float sum = s_part[l] + biasBreg;
      float gi = __shfl(sum, (l & 3));
      float gf = __shfl(sum, 2 + (l & 3) + 2);   // == 4 + (l&3)
      float gg = __shfl(sum, 8 + (l & 3));
      float go = __shfl(sum, 12 + (l & 3));
      if (l < 4){
        float cn = sigm(gf)*c2 + sigm(gi)*tanhf(gg);
        c2 = cn;
        AS(&h2b[wbuf*1024 + wid*4 + l], sigm(go)*tanhf(cn));
      }
    }
    __syncthreads();                       // drains all lanes' h2 stores
    if (tid == 0){
      asm volatile("s_waitcnt vmcnt(0)" ::: "memory");
      AS32(&fh2[wid], (unsigned)(t + 1));
    }
  }

  // ===== tail: y(T-1) from final h2 (buffer 0); wait all h2 published =====
  if (w == 0) poll4(fh2, (unsigned)T_STEPS);
  __syncthreads();
  *(float2*)&s_in[1536 + tid*2] = AL2(&h2b[tid*2]);
  __syncthreads();
  {
    int yrow = w >> 2, cb = (w & 3)*256 + l*4;
    float4 xv = *(float4*)&s_in[1536 + cb];
    float4 wv = *(float4*)&wy[yrow*1024 + cb];
    float yp = DOT4(wv, xv);
    #pragma unroll
    for (int mk = 32; mk; mk >>= 1) yp += __shfl_xor(yp, mk);
    if (l == 0) s_py[w] = yp;
  }
  __syncthreads();
  if (w == 0 && l == 0){
    out[(T_STEPS-1)*512 + wid*2    ] = s_py[0]+s_py[1]+s_py[2]+s_py[3] + bl0;
    out[(T_STEPS-1)*512 + wid*2 + 1] = s_py[4]+s_py[5]+s_py[6]+s_py[7] + bl1;
  }
}

// ---------------------------------------------------------------------------
extern "C" void kernel_launch(void* const* d_in, const int* in_sizes, int n_in,
                              void* d_out, int out_size, void* d_ws, size_t ws_size,
                              hipStream_t stream)
{
  const float* x    = (const float*)d_in[0];
  const float* Ws   = (const float*)d_in[1];
  const float* bs   = (const float*)d_in[2];
  const float* Wih1 = (const float*)d_in[3];
  const float* Whh1 = (const float*)d_in[4];
  const float* bih1 = (const float*)d_in[5];
  const float* bhh1 = (const float*)d_in[6];
  const float* Wih2 = (const float*)d_in[7];
  const float* Whh2 = (const float*)d_in[8];
  const float* bih2 = (const float*)d_in[9];
  const float* bhh2 = (const float*)d_in[10];
  const float* Wl   = (const float*)d_in[11];
  const float* bl   = (const float*)d_in[12];
  const float* Wm   = (const float*)d_in[13];
  const float* bm   = (const float*)d_in[14];
  char* wsb  = (char*)d_ws;
  float* out = (float*)d_out;

  // zero flags + recurrent state (fresh each call / graph replay)
  hipMemsetAsync(wsb, 0, WS_ZERO_BYTES, stream);

  feat_kernel<<<256, 512, 0, stream>>>(x, Ws, bs, (float*)(wsb + WS_FEAT));
  lstm_persist<<<NWG, 512, SMEM_BYTES, stream>>>(
      Wih1, Whh1, Wih2, Whh2, Wl, Wm,
      bih1, bhh1, bih2, bhh2, bl, bm, wsb, out);
  ls_kernel<<<T_STEPS, 64, 0, stream>>>(out);
}

// Round 9
// 36969.971 us; speedup vs baseline: 1.5419x; 1.5419x over previous
//
#include <hip/hip_runtime.h>
#include <math.h>

// ---------------------------------------------------------------------------
// LSTM_FEAT_2: T=4096 sequential 2-layer LSTM + log-softmax feedback.
// R9: R8 compute core (256wg x 512thr, 1 wg/CU via 133KB LDS, weights
// reg+LDS resident) with contention-free sync:
//  - aggregator wave (wg0/wave7, inside the syncthreads pattern) alone polls
//    the 256-flag arrays and publishes single-line epochs eh1/eh2;
//  - consumers poll epochs with ONE lane per wg (write-once lines);
//  - aggregator also gathers y, computes lse, publishes {lse,seq} in one
//    8B atomic store; 255 redundant gathers/lse removed;
//  - B's h2-half dot precomputed during A (pB), shortening B's path.
//
// Math (unchanged, verified R7/R8):
//   feat_t = Ws@x_t + bs                       (startup kernel)
//   gates1 = [Wih1s|Whh1]@[feat;h1] + WCL@h2 + biasA [+ biasE2 - rsWC*lse]
//     WCL=(Wih1e@Wm)@Wl, biasE2=Wih1e@bm+WC@bl, rsWC=rowsum(WC)
//   gates2 = [Wih2|Whh2]@[h1;h2] + biasB
//   y_t    = Wl@h2_t + bl -> d_out ; post-pass: out = log_softmax(out)
// ---------------------------------------------------------------------------

#define T_STEPS 4096
#define NWG 256

// ws layout (bytes)
#define WS_FH1   0            // 256 u32: h1 ready (value = steps done)
#define WS_FH2   4096         // 256 u32: h2 ready
#define WS_FY    8192         // 256 u32: y row published
#define WS_EH1   12288        // u32 epoch, own line
#define WS_EH2   12352        // u32 epoch, own line
#define WS_ELSE  12416        // u64 {lse_bits, seq}, own line
#define WS_H1    16384        // float[2][1024]
#define WS_H2    24576        // float[2][1024]
#define WS_ZERO_BYTES 32768
#define WS_FEAT  32768        // float[4096][512] -> end ~8.4MB

// dynamic LDS partition (floats)
#define OFF_WA 2560           // s_in[2560] | wa[16][1024] | wb[16][768] | wy[2][1024]
#define OFF_WB 18944
#define OFF_WY 31232
#define SMEM_FLOATS 33280
#define SMEM_BYTES  (SMEM_FLOATS*4)

#define PIN4(v) asm volatile("" : "+v"((v).x), "+v"((v).y), "+v"((v).z), "+v"((v).w))
#define PIN1(v) asm volatile("" : "+v"(v))
#define FMA4(acc,s,v4) {(acc).x += (s)*(v4).x; (acc).y += (s)*(v4).y; (acc).z += (s)*(v4).z; (acc).w += (s)*(v4).w;}
#define DOT4(a,b) ((a).x*(b).x + (a).y*(b).y + (a).z*(b).z + (a).w*(b).w)

__device__ __forceinline__ float AL(const float* p){
  return __hip_atomic_load(p, __ATOMIC_RELAXED, __HIP_MEMORY_SCOPE_AGENT);
}
__device__ __forceinline__ float2 AL2(const float* p){
  unsigned long long u = __hip_atomic_load((const unsigned long long*)p,
                                           __ATOMIC_RELAXED, __HIP_MEMORY_SCOPE_AGENT);
  union { unsigned long long u; float2 f; } c; c.u = u; return c.f;
}
__device__ __forceinline__ void AS(float* p, float v){
  __hip_atomic_store(p, v, __ATOMIC_RELAXED, __HIP_MEMORY_SCOPE_AGENT);
}
__device__ __forceinline__ void AS32(unsigned* p, unsigned v){
  __hip_atomic_store(p, v, __ATOMIC_RELAXED, __HIP_MEMORY_SCOPE_AGENT);
}
__device__ __forceinline__ unsigned AU_LD(const unsigned* p){
  return __hip_atomic_load(p, __ATOMIC_RELAXED, __HIP_MEMORY_SCOPE_AGENT);
}
__device__ __forceinline__ unsigned long long AU64_LD(const unsigned long long* p){
  return __hip_atomic_load(p, __ATOMIC_RELAXED, __HIP_MEMORY_SCOPE_AGENT);
}
__device__ __forceinline__ void AS64(unsigned long long* p, unsigned long long v){
  __hip_atomic_store(p, v, __ATOMIC_RELAXED, __HIP_MEMORY_SCOPE_AGENT);
}
__device__ __forceinline__ float sigm(float x){ return 1.0f/(1.0f+expf(-x)); }

// aggregator-only: lane l guards flags[4l..4l+3]; exits when all >= need.
__device__ __forceinline__ void poll4(const unsigned* flags, unsigned need){
  const int l = threadIdx.x & 63;
  const unsigned long long* p = (const unsigned long long*)(flags + 4*l);
  for(;;){
    unsigned long long a = __hip_atomic_load(p,     __ATOMIC_RELAXED, __HIP_MEMORY_SCOPE_AGENT);
    unsigned long long b = __hip_atomic_load(p + 1, __ATOMIC_RELAXED, __HIP_MEMORY_SCOPE_AGENT);
    if ((unsigned)a >= need && (unsigned)(a >> 32) >= need &&
        (unsigned)b >= need && (unsigned)(b >> 32) >= need) return;
    __builtin_amdgcn_s_sleep(1);
  }
}
// consumer: single-lane poll of a write-once epoch line
__device__ __forceinline__ void pollE(const unsigned* p, unsigned need){
  while (AU_LD(p) < need) __builtin_amdgcn_s_sleep(1);
}

// ---------------------------------------------------------------------------
// startup: feat[t][k] = Ws[k]·x[t] + bs[k]
__global__ __launch_bounds__(512) void feat_kernel(
    const float* __restrict__ x, const float* __restrict__ Ws,
    const float* __restrict__ bs, float* __restrict__ feat)
{
  __shared__ float s_x[16][360];
  __shared__ float s_w[512][20];
  const int bid = blockIdx.x, tid = threadIdx.x;
  const int t0 = bid * 16;
  for (int tt = 0; tt < 16; tt++)
    if (tid < 360) s_x[tt][tid] = x[(t0+tt)*360 + tid];
  float acc[16];
  #pragma unroll
  for (int i = 0; i < 16; i++) acc[i] = 0.f;
  for (int d0 = 0; d0 < 360; d0 += 16){
    const int dn = (360 - d0 < 16) ? (360 - d0) : 16;
    __syncthreads();
    if (dn == 16){
      #pragma unroll
      for (int c4 = 0; c4 < 4; c4++)
        *(float4*)&s_w[tid][c4*4] = *(const float4*)&Ws[tid*360 + d0 + c4*4];
    } else {
      for (int c = 0; c < dn; c++) s_w[tid][c] = Ws[tid*360 + d0 + c];
    }
    __syncthreads();
    for (int c = 0; c < dn; c++){
      float wv = s_w[tid][c];
      #pragma unroll
      for (int tt = 0; tt < 16; tt++) acc[tt] += wv * s_x[tt][d0 + c];
    }
  }
  for (int tt = 0; tt < 16; tt++)
    feat[(t0+tt)*512 + tid] = acc[tt] + bs[tid];
}

// ---------------------------------------------------------------------------
// post-pass: out[t] = out[t] - logsumexp(out[t])  (in place)
__global__ __launch_bounds__(64) void ls_kernel(float* __restrict__ out)
{
  const int t = blockIdx.x, l = threadIdx.x;
  float v[8];
  #pragma unroll
  for (int i = 0; i < 8; i++) v[i] = out[t*512 + l*8 + i];
  float m0 = v[0];
  #pragma unroll
  for (int i = 1; i < 8; i++) m0 = fmaxf(m0, v[i]);
  #pragma unroll
  for (int mk = 32; mk; mk >>= 1) m0 = fmaxf(m0, __shfl_xor(m0, mk));
  float s = 0.f;
  #pragma unroll
  for (int i = 0; i < 8; i++) s += expf(v[i] - m0);
  #pragma unroll
  for (int mk = 32; mk; mk >>= 1) s += __shfl_xor(s, mk);
  float lse = m0 + logf(s);
  #pragma unroll
  for (int i = 0; i < 8; i++) out[t*512 + l*8 + i] = v[i] - lse;
}

// ---------------------------------------------------------------------------
// persistent kernel: 256 wgs x 512 thr (8 waves). Wave w owns gate rows
// {2w, 2w+1}; lane l owns f4 col-chunks at dword 256*j + 4*l (bank-clean).
// wg0/wave7 additionally runs the aggregator (between its compute steps).
__global__ __launch_bounds__(512, 1) void lstm_persist(
    const float* __restrict__ Wih1, const float* __restrict__ Whh1,
    const float* __restrict__ Wih2, const float* __restrict__ Whh2,
    const float* __restrict__ Wl,   const float* __restrict__ Wm,
    const float* __restrict__ bih1, const float* __restrict__ bhh1,
    const float* __restrict__ bih2, const float* __restrict__ bhh2,
    const float* __restrict__ blp,  const float* __restrict__ bmp,
    char* __restrict__ wsb, float* __restrict__ out)
{
  extern __shared__ float smem[];
  float* s_in = smem;               // 2560: A: [feat|h1|h2]; B restages h1 only
  float* wa   = smem + OFF_WA;      // [16][1024] = WCL rows
  float* wb   = smem + OFF_WB;      // [16][768]  = Whh2 cols 256..1023 (init: WCtmp)
  float* wy   = smem + OFF_WY;      // [2][1024]  = Wl rows wid*2, wid*2+1
  __shared__ float s_part[16];
  __shared__ float s_py[8];
  __shared__ float s_sums[32];

  unsigned* fh1 = (unsigned*)(wsb + WS_FH1);
  unsigned* fh2 = (unsigned*)(wsb + WS_FH2);
  unsigned* fy  = (unsigned*)(wsb + WS_FY);
  unsigned* eh1p = (unsigned*)(wsb + WS_EH1);
  unsigned* eh2p = (unsigned*)(wsb + WS_EH2);
  unsigned long long* elsep = (unsigned long long*)(wsb + WS_ELSE);
  float* h1b = (float*)(wsb + WS_H1);
  float* h2b = (float*)(wsb + WS_H2);
  const float* featp = (const float*)(wsb + WS_FEAT);

  const int wid = blockIdx.x, tid = threadIdx.x;
  const int w = tid >> 6, l = tid & 63;
  const bool isAgg = (wid == 0 && w == 7);
  const int o0 = 2*w, o1 = 2*w + 1;
  const int rA0 = (o0 >> 2)*1024 + wid*4 + (o0 & 3);
  const int rA1 = (o1 >> 2)*1024 + wid*4 + (o1 & 3);

  // ===== init 1: stage this wg's 16 Wih1e rows (16x128) into s_in =====
  for (int idx = tid; idx < 2048; idx += 512){
    int o = idx >> 7, e = idx & 127;
    int r = (o >> 2)*1024 + wid*4 + (o & 3);
    s_in[idx] = Wih1[r*640 + 512 + e];
  }
  __syncthreads();

  // ===== init 2: WCtmp = Wih1e @ Wm  (16x512) -> wb area =====
  {
    float4 a00 = {0,0,0,0}, a01 = a00, a10 = a00, a11 = a00;
    for (int e = 0; e < 128; e++){
      float w0e = s_in[o0*128 + e], w1e = s_in[o1*128 + e];
      float4 m0 = *(const float4*)&Wm[e*512 + l*4];
      float4 m1 = *(const float4*)&Wm[e*512 + l*4 + 256];
      FMA4(a00, w0e, m0); FMA4(a01, w0e, m1);
      FMA4(a10, w1e, m0); FMA4(a11, w1e, m1);
    }
    *(float4*)&wb[o0*512 + l*4]       = a00;
    *(float4*)&wb[o0*512 + l*4 + 256] = a01;
    *(float4*)&wb[o1*512 + l*4]       = a10;
    *(float4*)&wb[o1*512 + l*4 + 256] = a11;
  }
  __syncthreads();

  // ===== init 3: WCL = WCtmp @ Wl (16x1024) -> wa; rowsum/bl piggyback =====
  {
    float4 c00={0,0,0,0}, c01=c00, c02=c00, c03=c00;
    float4 c10=c00, c11=c00, c12=c00, c13=c00;
    float rs0=0.f, rs1=0.f, wl0=0.f, wl1=0.f;
    for (int m = 0; m < 512; m++){
      float t0 = wb[o0*512 + m], t1 = wb[o1*512 + m];
      float blm = blp[m];
      rs0 += t0; wl0 += t0*blm; rs1 += t1; wl1 += t1*blm;
      float4 q0 = *(const float4*)&Wl[m*1024 + l*4];
      float4 q1 = *(const float4*)&Wl[m*1024 + l*4 + 256];
      float4 q2 = *(const float4*)&Wl[m*1024 + l*4 + 512];
      float4 q3 = *(const float4*)&Wl[m*1024 + l*4 + 768];
      FMA4(c00,t0,q0); FMA4(c01,t0,q1); FMA4(c02,t0,q2); FMA4(c03,t0,q3);
      FMA4(c10,t1,q0); FMA4(c11,t1,q1); FMA4(c12,t1,q2); FMA4(c13,t1,q3);
    }
    *(float4*)&wa[o0*1024 + l*4      ] = c00;
    *(float4*)&wa[o0*1024 + l*4 + 256] = c01;
    *(float4*)&wa[o0*1024 + l*4 + 512] = c02;
    *(float4*)&wa[o0*1024 + l*4 + 768] = c03;
    *(float4*)&wa[o1*1024 + l*4      ] = c10;
    *(float4*)&wa[o1*1024 + l*4 + 256] = c11;
    *(float4*)&wa[o1*1024 + l*4 + 512] = c12;
    *(float4*)&wa[o1*1024 + l*4 + 768] = c13;
    if (l == 0){
      s_sums[w*4+0] = rs0; s_sums[w*4+1] = rs1;
      s_sums[w*4+2] = wl0; s_sums[w*4+3] = wl1;
    }
  }
  __syncthreads();

  // ===== init 4: per-row bias regs (wave 0) =====
  float biasAreg=0.f, biasBreg=0.f, bE2reg=0.f, rsReg=0.f;
  float bl0=0.f, bl1=0.f, c1=0.f, c2=0.f;
  if (w == 0 && l < 16){
    int r = (l >> 2)*1024 + wid*4 + (l & 3);
    biasAreg = bih1[r] + bhh1[r];
    biasBreg = bih2[r] + bhh2[r];
    rsReg = s_sums[(l>>1)*4 + (l&1)];
    float acc = s_sums[(l>>1)*4 + 2 + (l&1)];
    for (int e = 0; e < 128; e++) acc += s_in[l*128 + e] * bmp[e];
    bE2reg = acc;
  }
  if (w == 0 && l == 0){ bl0 = blp[wid*2]; bl1 = blp[wid*2 + 1]; }

  // ===== init 5: LDS weights wb (Whh2 cols 256..1023) and wy (Wl rows) =====
  for (int o = 0; o < 16; o++){
    int r = (o >> 2)*1024 + wid*4 + (o & 3);
    for (int c = tid; c < 768; c += 512)
      wb[o*768 + c] = Whh2[r*1024 + 256 + c];
  }
  for (int idx = tid; idx < 2048; idx += 512){
    int row = idx >> 10, c = idx & 1023;
    wy[idx] = Wl[(wid*2 + row)*1024 + c];
  }

  // ===== init 6: pinned register weights (88 floats/thread) =====
  float4 wA0[6], wA1[6], wB0[5], wB1[5];
  #pragma unroll
  for (int j = 0; j < 6; j++){
    int c = 256*j + l*4;
    wA0[j] = (c < 512) ? *(const float4*)&Wih1[rA0*640 + c]
                       : *(const float4*)&Whh1[rA0*1024 + c - 512];
    wA1[j] = (c < 512) ? *(const float4*)&Wih1[rA1*640 + c]
                       : *(const float4*)&Whh1[rA1*1024 + c - 512];
  }
  #pragma unroll
  for (int j = 0; j < 5; j++){
    int c = 256*j + l*4;
    wB0[j] = (c < 1024) ? *(const float4*)&Wih2[rA0*1024 + c]
                        : *(const float4*)&Whh2[rA0*1024 + c - 1024];
    wB1[j] = (c < 1024) ? *(const float4*)&Wih2[rA1*1024 + c]
                        : *(const float4*)&Whh2[rA1*1024 + c - 1024];
  }
  #pragma unroll
  for (int j = 0; j < 6; j++){ PIN4(wA0[j]); PIN4(wA1[j]); }
  #pragma unroll
  for (int j = 0; j < 5; j++){ PIN4(wB0[j]); PIN4(wB1[j]); }
  PIN1(biasAreg); PIN1(biasBreg); PIN1(bE2reg); PIN1(rsReg);
  PIN1(bl0); PIN1(bl1);
  __syncthreads();

  // ===== main loop =====
  for (int t = 0; t < T_STEPS; t++){
    const int rb = t & 1, wbuf = (t + 1) & 1;

    // ---- A gate: aggregator folds fh2 -> eh2; consumers poll eh2 (1 lane)
    if (t > 0){
      if (isAgg){ poll4(fh2, (unsigned)t); AS32(eh2p, (unsigned)t); }
      if (w == 0 && l == 0) pollE(eh2p, (unsigned)t);
    }
    __syncthreads();

    // ---- phase A stage: s_in = [feat(512) | h1(1024) | h2(1024)] ----
    {
      int s1 = tid*2;
      float2 v1 = (s1 < 512) ? *(const float2*)&featp[t*512 + s1]
                             : AL2(&h1b[rb*1024 + s1 - 512]);
      *(float2*)&s_in[s1] = v1;
      int s2 = 1024 + tid*2;
      float2 v2 = (tid < 256) ? AL2(&h1b[rb*1024 + s2 - 512])
                              : AL2(&h2b[rb*1024 + s2 - 1536]);
      *(float2*)&s_in[s2] = v2;
      if (tid < 256)
        *(float2*)&s_in[2048 + tid*2] = AL2(&h2b[rb*1024 + 512 + tid*2]);
    }
    __syncthreads();

    // ---- y(t-1) rows (overlap): waves 0-3 row wid*2, waves 4-7 row wid*2+1
    if (t > 0){
      int yrow = w >> 2, cb = (w & 3)*256 + l*4;
      float4 xv = *(float4*)&s_in[1536 + cb];
      float4 wv = *(float4*)&wy[yrow*1024 + cb];
      float yp = DOT4(wv, xv);
      #pragma unroll
      for (int mk = 32; mk; mk >>= 1) yp += __shfl_xor(yp, mk);
      if (l == 0) s_py[w] = yp;
    }
    __syncthreads();
    if (t > 0 && w == 0 && l == 0){
      float y0 = s_py[0]+s_py[1]+s_py[2]+s_py[3] + bl0;
      float y1 = s_py[4]+s_py[5]+s_py[6]+s_py[7] + bl1;
      union { struct { float a, b; } f; unsigned long long v; } pk;
      pk.f.a = y0; pk.f.b = y1;
      AS64((unsigned long long*)&out[(size_t)(t-1)*512 + wid*2], pk.v);
      asm volatile("s_waitcnt vmcnt(0)" ::: "memory");
      AS32(&fy[wid], (unsigned)t);
    }

    // ---- aggregator: gather y(t-1), compute lse, publish {lse, t} ----
    if (t > 0 && isAgg){
      poll4(fy, (unsigned)t);
      const float* yr = &out[(size_t)(t-1)*512];
      float2 q0 = AL2(yr + l*8),     q1 = AL2(yr + l*8 + 2);
      float2 q2 = AL2(yr + l*8 + 4), q3 = AL2(yr + l*8 + 6);
      float m0 = fmaxf(fmaxf(fmaxf(q0.x,q0.y), fmaxf(q1.x,q1.y)),
                       fmaxf(fmaxf(q2.x,q2.y), fmaxf(q3.x,q3.y)));
      #pragma unroll
      for (int mk = 32; mk; mk >>= 1) m0 = fmaxf(m0, __shfl_xor(m0, mk));
      float s = expf(q0.x-m0)+expf(q0.y-m0)+expf(q1.x-m0)+expf(q1.y-m0)
              + expf(q2.x-m0)+expf(q2.y-m0)+expf(q3.x-m0)+expf(q3.y-m0);
      #pragma unroll
      for (int mk = 32; mk; mk >>= 1) s += __shfl_xor(s, mk);
      float lv = m0 + logf(s);
      if (l == 0){
        union { struct { unsigned lo, hi; } u; unsigned long long v; } pk;
        pk.u.lo = __float_as_uint(lv); pk.u.hi = (unsigned)t;
        AS64(elsep, pk.v);
      }
    }

    // ---- gates1 dot: regs j=0..5 (feat|h1) + LDS k=0..3 (WCL @ h2) ----
    float acc0 = 0.f, acc1 = 0.f;
    #pragma unroll
    for (int j = 0; j < 6; j++){
      float4 xv = *(float4*)&s_in[256*j + l*4];
      acc0 += DOT4(wA0[j], xv); acc1 += DOT4(wA1[j], xv);
    }
    #pragma unroll
    for (int k = 0; k < 4; k++){
      float4 xv = *(float4*)&s_in[1536 + 256*k + l*4];
      float4 u0 = *(float4*)&wa[o0*1024 + 256*k + l*4];
      float4 u1 = *(float4*)&wa[o1*1024 + 256*k + l*4];
      acc0 += DOT4(u0, xv); acc1 += DOT4(u1, xv);
    }
    #pragma unroll
    for (int mk = 32; mk; mk >>= 1){
      acc0 += __shfl_xor(acc0, mk); acc1 += __shfl_xor(acc1, mk);
    }
    if (l == 0){ s_part[o0] = acc0; s_part[o1] = acc1; }

    // ---- pB: precompute B's h2-dependent half (h2 stays in s_in[1536..)) --
    float pB0, pB1;
    {
      float4 xv = *(float4*)&s_in[1536 + l*4];
      pB0 = DOT4(wB0[4], xv); pB1 = DOT4(wB1[4], xv);
      #pragma unroll
      for (int k = 0; k < 3; k++){
        float4 x2 = *(float4*)&s_in[1536 + 256 + 256*k + l*4];
        float4 u0 = *(float4*)&wb[o0*768 + 256*k + l*4];
        float4 u1 = *(float4*)&wb[o1*768 + 256*k + l*4];
        pB0 += DOT4(u0, x2); pB1 += DOT4(u1, x2);
      }
    }
    __syncthreads();

    // ---- finalize A: wave0 polls {lse,seq} (1 lane, 1 line), updates h1 ----
    if (w == 0){
      float lse = 0.f;
      if (t > 0){
        if (l == 0){
          for(;;){
            unsigned long long v = AU64_LD(elsep);
            if ((unsigned)(v >> 32) >= (unsigned)t){
              lse = __uint_as_float((unsigned)(v & 0xffffffffu)); break;
            }
            __builtin_amdgcn_s_sleep(1);
          }
        }
        lse = __shfl(lse, 0);
      }
      if (l < 16){
        float sum = s_part[l] + biasAreg;
        if (t > 0) sum += bE2reg - rsReg*lse;
        float gi = __shfl(sum, (l & 3));
        float gf = __shfl(sum, 4 + (l & 3));
        float gg = __shfl(sum, 8 + (l & 3));
        float go = __shfl(sum, 12 + (l & 3));
        if (l < 4){
          float cn = sigm(gf)*c1 + sigm(gi)*tanhf(gg);
          c1 = cn;
          AS(&h1b[wbuf*1024 + wid*4 + l], sigm(go)*tanhf(cn));
        }
      }
    }
    __syncthreads();                       // drains h1 stores (barrier waitcnt)
    if (tid == 0) AS32(&fh1[wid], (unsigned)(t + 1));

    // ---- B gate: aggregator folds fh1 -> eh1; consumers poll eh1 ----
    if (isAgg){ poll4(fh1, (unsigned)(t + 1)); AS32(eh1p, (unsigned)(t + 1)); }
    if (w == 0 && l == 0) pollE(eh1p, (unsigned)(t + 1));
    __syncthreads();

    // ---- phase B stage: restage h1 only ----
    *(float2*)&s_in[tid*2] = AL2(&h1b[wbuf*1024 + tid*2]);
    __syncthreads();

    // ---- gates2 dot: regs j=0..3 (h1) + precomputed pB (h2 half) ----
    float b0 = pB0, b1 = pB1;
    #pragma unroll
    for (int j = 0; j < 4; j++){
      float4 xv = *(float4*)&s_in[256*j + l*4];
      b0 += DOT4(wB0[j], xv); b1 += DOT4(wB1[j], xv);
    }
    #pragma unroll
    for (int mk = 32; mk; mk >>= 1){
      b0 += __shfl_xor(b0, mk); b1 += __shfl_xor(b1, mk);
    }
    if (l == 0){ s_part[o0] = b0; s_part[o1] = b1; }
    __syncthreads();
    if (w == 0 && l < 16){
      float sum = s_part[l] + biasBreg;
      float gi = __shfl(sum, (l & 3));
      float gf = __shfl(sum, 4 + (l & 3));
      float gg = __shfl(sum, 8 + (l & 3));
      float go = __shfl(sum, 12 + (l & 3));
      if (l < 4){
        float cn = sigm(gf)*c2 + sigm(gi)*tanhf(gg);
        c2 = cn;
        AS(&h2b[wbuf*1024 + wid*4 + l], sigm(go)*tanhf(cn));
      }
    }
    __syncthreads();                       // drains h2 stores
    if (tid == 0) AS32(&fh2[wid], (unsigned)(t + 1));
  }

  // ===== tail: y(T-1) from final h2 (buffer 0) =====
  if (isAgg){ poll4(fh2, (unsigned)T_STEPS); AS32(eh2p, (unsigned)T_STEPS); }
  if (w == 0 && l == 0) pollE(eh2p, (unsigned)T_STEPS);
  __syncthreads();
  *(float2*)&s_in[1536 + tid*2] = AL2(&h2b[tid*2]);
  __syncthreads();
  {
    int yrow = w >> 2, cb = (w & 3)*256 + l*4;
    float4 xv = *(float4*)&s_in[1536 + cb];
    float4 wv = *(float4*)&wy[yrow*1024 + cb];
    float yp = DOT4(wv, xv);
    #pragma unroll
    for (int mk = 32; mk; mk >>= 1) yp += __shfl_xor(yp, mk);
    if (l == 0) s_py[w] = yp;
  }
  __syncthreads();
  if (w == 0 && l == 0){
    out[(T_STEPS-1)*512 + wid*2    ] = s_py[0]+s_py[1]+s_py[2]+s_py[3] + bl0;
    out[(T_STEPS-1)*512 + wid*2 + 1] = s_py[4]+s_py[5]+s_py[6]+s_py[7] + bl1;
  }
}

// ---------------------------------------------------------------------------
extern "C" void kernel_launch(void* const* d_in, const int* in_sizes, int n_in,
                              void* d_out, int out_size, void* d_ws, size_t ws_size,
                              hipStream_t stream)
{
  const float* x    = (const float*)d_in[0];
  const float* Ws   = (const float*)d_in[1];
  const float* bs   = (const float*)d_in[2];
  const float* Wih1 = (const float*)d_in[3];
  const float* Whh1 = (const float*)d_in[4];
  const float* bih1 = (const float*)d_in[5];
  const float* bhh1 = (const float*)d_in[6];
  const float* Wih2 = (const float*)d_in[7];
  const float* Whh2 = (const float*)d_in[8];
  const float* bih2 = (const float*)d_in[9];
  const float* bhh2 = (const float*)d_in[10];
  const float* Wl   = (const float*)d_in[11];
  const float* bl   = (const float*)d_in[12];
  const float* Wm   = (const float*)d_in[13];
  const float* bm   = (const float*)d_in[14];
  char* wsb  = (char*)d_ws;
  float* out = (float*)d_out;

  // zero flags/epochs + recurrent state (fresh each call / graph replay)
  hipMemsetAsync(wsb, 0, WS_ZERO_BYTES, stream);

  feat_kernel<<<256, 512, 0, stream>>>(x, Ws, bs, (float*)(wsb + WS_FEAT));
  lstm_persist<<<NWG, 512, SMEM_BYTES, stream>>>(
      Wih1, Whh1, Wih2, Whh2, Wl, Wm,
      bih1, bhh1, bih2, bhh2, bl, bm, wsb, out);
  ls_kernel<<<T_STEPS, 64, 0, stream>>>(out);
}

// Round 10
// 29686.407 us; speedup vs baseline: 1.9202x; 1.2454x over previous
//
#include <hip/hip_runtime.h>
#include <math.h>

// ---------------------------------------------------------------------------
// LSTM_FEAT_2: T=4096 sequential 2-layer LSTM + log-softmax feedback.
// R10: fused data+seq 16B records replace all barriers/epochs.
//  - producer publishes {h0,h1,seq,0} as ONE global_store_dwordx4 (sc0 sc1):
//    transactional 16B -> consumer's single dwordx4 load that sees seq also
//    sees the matching data. Poll == data load. Depth ~2RT per exchange
//    (was ~5-6RT with aggregator+epoch in R9).
//  - each of 512 consumer threads spins on ITS OWN record (wave-coalesced
//    1KB/load-instr), deposits to LDS, __syncthreads combines.
//  - lse: per-wg y-records {y0,y1,seq}; wave0 wide-polls 4KB AFTER gates1
//    dot (flight hidden), reduces locally. No aggregator, no elsep.
//  - h1b/h2b global buffers deleted (records carry state). Double-buffer
//    parity + monotone seq; overwrite safety proven via A(t+2) <= B(t+1)
//    <= A(t+1) happens-before chain.
//
// Math (unchanged, verified R7-R9):
//   feat_t = Ws@x_t + bs                       (startup kernel)
//   gates1 = [Wih1s|Whh1]@[feat;h1] + WCL@h2 + biasA [+ biasE2 - rsWC*lse]
//     WCL=(Wih1e@Wm)@Wl, biasE2=Wih1e@bm+WC@bl, rsWC=rowsum(WC)
//   gates2 = [Wih2|Whh2]@[h1;h2] + biasB
//   y_t    = Wl@h2_t + bl -> d_out ; post-pass: out = log_softmax(out)
// ---------------------------------------------------------------------------

#define T_STEPS 4096
#define NWG 256

typedef unsigned u32x4 __attribute__((ext_vector_type(4)));

// ws layout (bytes)
#define WS_RH1   0            // u32x4[2][512]: h1 records {h,h,seq,0} (16KB)
#define WS_RH2   16384        // u32x4[2][512]: h2 records (16KB)
#define WS_RY    32768        // u32x4[2][256]: y  records {y0,y1,seq,0} (8KB)
#define WS_ZERO_BYTES 40960
#define WS_FEAT  40960        // float[4096][512] -> end ~8.4MB

// dynamic LDS partition (floats)
#define OFF_WA 2560           // s_in[2560] | wa[16][1024] | wb[16][768] | wy[2][1024]
#define OFF_WB 18944
#define OFF_WY 31232
#define SMEM_FLOATS 33280
#define SMEM_BYTES  (SMEM_FLOATS*4)

#define PIN4(v) asm volatile("" : "+v"((v).x), "+v"((v).y), "+v"((v).z), "+v"((v).w))
#define PIN1(v) asm volatile("" : "+v"(v))
#define FMA4(acc,s,v4) {(acc).x += (s)*(v4).x; (acc).y += (s)*(v4).y; (acc).z += (s)*(v4).z; (acc).w += (s)*(v4).w;}
#define DOT4(a,b) ((a).x*(b).x + (a).y*(b).y + (a).z*(b).z + (a).w*(b).w)

// coherent 16B transactional load/store (bypass L1/L2 -> LLC)
__device__ __forceinline__ u32x4 ld16(const u32x4* p){
  u32x4 r;
  asm volatile("global_load_dwordx4 %0, %1, off sc0 sc1\n\ts_waitcnt vmcnt(0)"
               : "=v"(r) : "v"(p) : "memory");
  return r;
}
__device__ __forceinline__ void st16(u32x4* p, u32x4 v){
  asm volatile("global_store_dwordx4 %0, %1, off sc0 sc1"
               :: "v"(p), "v"(v) : "memory");
}
__device__ __forceinline__ float sigm(float x){ return 1.0f/(1.0f+expf(-x)); }

// ---------------------------------------------------------------------------
// startup: feat[t][k] = Ws[k]·x[t] + bs[k]
__global__ __launch_bounds__(512) void feat_kernel(
    const float* __restrict__ x, const float* __restrict__ Ws,
    const float* __restrict__ bs, float* __restrict__ feat)
{
  __shared__ float s_x[16][360];
  __shared__ float s_w[512][20];
  const int bid = blockIdx.x, tid = threadIdx.x;
  const int t0 = bid * 16;
  for (int tt = 0; tt < 16; tt++)
    if (tid < 360) s_x[tt][tid] = x[(t0+tt)*360 + tid];
  float acc[16];
  #pragma unroll
  for (int i = 0; i < 16; i++) acc[i] = 0.f;
  for (int d0 = 0; d0 < 360; d0 += 16){
    const int dn = (360 - d0 < 16) ? (360 - d0) : 16;
    __syncthreads();
    if (dn == 16){
      #pragma unroll
      for (int c4 = 0; c4 < 4; c4++)
        *(float4*)&s_w[tid][c4*4] = *(const float4*)&Ws[tid*360 + d0 + c4*4];
    } else {
      for (int c = 0; c < dn; c++) s_w[tid][c] = Ws[tid*360 + d0 + c];
    }
    __syncthreads();
    for (int c = 0; c < dn; c++){
      float wv = s_w[tid][c];
      #pragma unroll
      for (int tt = 0; tt < 16; tt++) acc[tt] += wv * s_x[tt][d0 + c];
    }
  }
  for (int tt = 0; tt < 16; tt++)
    feat[(t0+tt)*512 + tid] = acc[tt] + bs[tid];
}

// ---------------------------------------------------------------------------
// post-pass: out[t] = out[t] - logsumexp(out[t])  (in place)
__global__ __launch_bounds__(64) void ls_kernel(float* __restrict__ out)
{
  const int t = blockIdx.x, l = threadIdx.x;
  float v[8];
  #pragma unroll
  for (int i = 0; i < 8; i++) v[i] = out[t*512 + l*8 + i];
  float m0 = v[0];
  #pragma unroll
  for (int i = 1; i < 8; i++) m0 = fmaxf(m0, v[i]);
  #pragma unroll
  for (int mk = 32; mk; mk >>= 1) m0 = fmaxf(m0, __shfl_xor(m0, mk));
  float s = 0.f;
  #pragma unroll
  for (int i = 0; i < 8; i++) s += expf(v[i] - m0);
  #pragma unroll
  for (int mk = 32; mk; mk >>= 1) s += __shfl_xor(s, mk);
  float lse = m0 + logf(s);
  #pragma unroll
  for (int i = 0; i < 8; i++) out[t*512 + l*8 + i] = v[i] - lse;
}

// ---------------------------------------------------------------------------
// persistent kernel: 256 wgs x 512 thr (8 waves), 1 wg/CU via 133KB LDS.
// Wave w owns gate rows {2w,2w+1}; lane l owns f4 col-chunks (bank-clean).
// wg owns h rows wid*4..wid*4+3 (both layers) and y rows wid*2, wid*2+1.
__global__ __launch_bounds__(512, 1) void lstm_persist(
    const float* __restrict__ Wih1, const float* __restrict__ Whh1,
    const float* __restrict__ Wih2, const float* __restrict__ Whh2,
    const float* __restrict__ Wl,   const float* __restrict__ Wm,
    const float* __restrict__ bih1, const float* __restrict__ bhh1,
    const float* __restrict__ bih2, const float* __restrict__ bhh2,
    const float* __restrict__ blp,  const float* __restrict__ bmp,
    char* __restrict__ wsb, float* __restrict__ out)
{
  extern __shared__ float smem[];
  float* s_in = smem;               // A: [feat|h1|h2]; B: h1 at [0..1024)
  float* wa   = smem + OFF_WA;      // [16][1024] = WCL rows
  float* wb   = smem + OFF_WB;      // [16][768]  = Whh2 cols 256..1023 (init: WCtmp)
  float* wy   = smem + OFF_WY;      // [2][1024]  = Wl rows wid*2, wid*2+1
  __shared__ float s_part[16];
  __shared__ float s_py[8];
  __shared__ float s_sums[32];

  u32x4* rh1 = (u32x4*)(wsb + WS_RH1);   // [2][512]
  u32x4* rh2 = (u32x4*)(wsb + WS_RH2);   // [2][512]
  u32x4* ry  = (u32x4*)(wsb + WS_RY);    // [2][256]
  const float* featp = (const float*)(wsb + WS_FEAT);

  const int wid = blockIdx.x, tid = threadIdx.x;
  const int w = tid >> 6, l = tid & 63;
  const int o0 = 2*w, o1 = 2*w + 1;
  const int rA0 = (o0 >> 2)*1024 + wid*4 + (o0 & 3);
  const int rA1 = (o1 >> 2)*1024 + wid*4 + (o1 & 3);

  // ===== init 1: stage this wg's 16 Wih1e rows (16x128) into s_in =====
  for (int idx = tid; idx < 2048; idx += 512){
    int o = idx >> 7, e = idx & 127;
    int r = (o >> 2)*1024 + wid*4 + (o & 3);
    s_in[idx] = Wih1[r*640 + 512 + e];
  }
  __syncthreads();

  // ===== init 2: WCtmp = Wih1e @ Wm  (16x512) -> wb area =====
  {
    float4 a00 = {0,0,0,0}, a01 = a00, a10 = a00, a11 = a00;
    for (int e = 0; e < 128; e++){
      float w0e = s_in[o0*128 + e], w1e = s_in[o1*128 + e];
      float4 m0 = *(const float4*)&Wm[e*512 + l*4];
      float4 m1 = *(const float4*)&Wm[e*512 + l*4 + 256];
      FMA4(a00, w0e, m0); FMA4(a01, w0e, m1);
      FMA4(a10, w1e, m0); FMA4(a11, w1e, m1);
    }
    *(float4*)&wb[o0*512 + l*4]       = a00;
    *(float4*)&wb[o0*512 + l*4 + 256] = a01;
    *(float4*)&wb[o1*512 + l*4]       = a10;
    *(float4*)&wb[o1*512 + l*4 + 256] = a11;
  }
  __syncthreads();

  // ===== init 3: WCL = WCtmp @ Wl (16x1024) -> wa; rowsum/bl piggyback =====
  {
    float4 c00={0,0,0,0}, c01=c00, c02=c00, c03=c00;
    float4 c10=c00, c11=c00, c12=c00, c13=c00;
    float rs0=0.f, rs1=0.f, wl0=0.f, wl1=0.f;
    for (int m = 0; m < 512; m++){
      float t0 = wb[o0*512 + m], t1 = wb[o1*512 + m];
      float blm = blp[m];
      rs0 += t0; wl0 += t0*blm; rs1 += t1; wl1 += t1*blm;
      float4 q0 = *(const float4*)&Wl[m*1024 + l*4];
      float4 q1 = *(const float4*)&Wl[m*1024 + l*4 + 256];
      float4 q2 = *(const float4*)&Wl[m*1024 + l*4 + 512];
      float4 q3 = *(const float4*)&Wl[m*1024 + l*4 + 768];
      FMA4(c00,t0,q0); FMA4(c01,t0,q1); FMA4(c02,t0,q2); FMA4(c03,t0,q3);
      FMA4(c10,t1,q0); FMA4(c11,t1,q1); FMA4(c12,t1,q2); FMA4(c13,t1,q3);
    }
    *(float4*)&wa[o0*1024 + l*4      ] = c00;
    *(float4*)&wa[o0*1024 + l*4 + 256] = c01;
    *(float4*)&wa[o0*1024 + l*4 + 512] = c02;
    *(float4*)&wa[o0*1024 + l*4 + 768] = c03;
    *(float4*)&wa[o1*1024 + l*4      ] = c10;
    *(float4*)&wa[o1*1024 + l*4 + 256] = c11;
    *(float4*)&wa[o1*1024 + l*4 + 512] = c12;
    *(float4*)&wa[o1*1024 + l*4 + 768] = c13;
    if (l == 0){
      s_sums[w*4+0] = rs0; s_sums[w*4+1] = rs1;
      s_sums[w*4+2] = wl0; s_sums[w*4+3] = wl1;
    }
  }
  __syncthreads();

  // ===== init 4: per-row bias regs (wave 0) =====
  float biasAreg=0.f, biasBreg=0.f, bE2reg=0.f, rsReg=0.f;
  float bl0=0.f, bl1=0.f, c1=0.f, c2=0.f;
  if (w == 0 && l < 16){
    int r = (l >> 2)*1024 + wid*4 + (l & 3);
    biasAreg = bih1[r] + bhh1[r];
    biasBreg = bih2[r] + bhh2[r];
    rsReg = s_sums[(l>>1)*4 + (l&1)];
    float acc = s_sums[(l>>1)*4 + 2 + (l&1)];
    for (int e = 0; e < 128; e++) acc += s_in[l*128 + e] * bmp[e];
    bE2reg = acc;
  }
  if (w == 0 && l == 0){ bl0 = blp[wid*2]; bl1 = blp[wid*2 + 1]; }

  // ===== init 5: LDS weights wb (Whh2 cols 256..1023) and wy (Wl rows) =====
  for (int o = 0; o < 16; o++){
    int r = (o >> 2)*1024 + wid*4 + (o & 3);
    for (int c = tid; c < 768; c += 512)
      wb[o*768 + c] = Whh2[r*1024 + 256 + c];
  }
  for (int idx = tid; idx < 2048; idx += 512){
    int row = idx >> 10, c = idx & 1023;
    wy[idx] = Wl[(wid*2 + row)*1024 + c];
  }

  // ===== init 6: pinned register weights (88 floats/thread) =====
  float4 wA0[6], wA1[6], wB0[5], wB1[5];
  #pragma unroll
  for (int j = 0; j < 6; j++){
    int c = 256*j + l*4;
    wA0[j] = (c < 512) ? *(const float4*)&Wih1[rA0*640 + c]
                       : *(const float4*)&Whh1[rA0*1024 + c - 512];
    wA1[j] = (c < 512) ? *(const float4*)&Wih1[rA1*640 + c]
                       : *(const float4*)&Whh1[rA1*1024 + c - 512];
  }
  #pragma unroll
  for (int j = 0; j < 5; j++){
    int c = 256*j + l*4;
    wB0[j] = (c < 1024) ? *(const float4*)&Wih2[rA0*1024 + c]
                        : *(const float4*)&Whh2[rA0*1024 + c - 1024];
    wB1[j] = (c < 1024) ? *(const float4*)&Wih2[rA1*1024 + c]
                        : *(const float4*)&Whh2[rA1*1024 + c - 1024];
  }
  #pragma unroll
  for (int j = 0; j < 6; j++){ PIN4(wA0[j]); PIN4(wA1[j]); }
  #pragma unroll
  for (int j = 0; j < 5; j++){ PIN4(wB0[j]); PIN4(wB1[j]); }
  PIN1(biasAreg); PIN1(biasBreg); PIN1(bE2reg); PIN1(rsReg);
  PIN1(bl0); PIN1(bl1);
  __syncthreads();

  // ===== main loop =====
  for (int t = 0; t < T_STEPS; t++){
    const int pprev = (t + 1) & 1;       // parity of step t-1
    const int pcur  = t & 1;             // parity of step t

    // ---- phase A stage: feat plain; h1(t-1),h2(t-1) via fused records ----
    if (tid < 256)
      *(float2*)&s_in[tid*2] = *(const float2*)&featp[(size_t)t*512 + tid*2];
    if (t > 0){
      const u32x4* p1 = rh1 + pprev*512 + tid;
      const u32x4* p2 = rh2 + pprev*512 + tid;
      u32x4 a, b; bool d1 = false, d2 = false;
      for(;;){
        if (!d1){ a = ld16(p1); d1 = (a.z >= (unsigned)t); }
        if (!d2){ b = ld16(p2); d2 = (b.z >= (unsigned)t); }
        if (d1 && d2) break;
        __builtin_amdgcn_s_sleep(1);
      }
      s_in[512  + 2*tid] = __uint_as_float(a.x);
      s_in[512  + 2*tid + 1] = __uint_as_float(a.y);
      s_in[1536 + 2*tid] = __uint_as_float(b.x);
      s_in[1536 + 2*tid + 1] = __uint_as_float(b.y);
    } else {
      s_in[512  + 2*tid] = 0.f; s_in[512  + 2*tid + 1] = 0.f;
      s_in[1536 + 2*tid] = 0.f; s_in[1536 + 2*tid + 1] = 0.f;
    }
    __syncthreads();

    // ---- y(t-1) partials: waves 0-3 row wid*2, waves 4-7 row wid*2+1 ----
    if (t > 0){
      int yrow = w >> 2, cb = (w & 3)*256 + l*4;
      float4 xv = *(float4*)&s_in[1536 + cb];
      float4 wv = *(float4*)&wy[yrow*1024 + cb];
      float yp = DOT4(wv, xv);
      #pragma unroll
      for (int mk = 32; mk; mk >>= 1) yp += __shfl_xor(yp, mk);
      if (l == 0) s_py[w] = yp;
    }
    __syncthreads();

    // ---- publish y(t-1) record early (flight hides under gates1 dot) ----
    if (t > 0 && w == 0 && l == 0){
      float y0 = s_py[0]+s_py[1]+s_py[2]+s_py[3] + bl0;
      float y1 = s_py[4]+s_py[5]+s_py[6]+s_py[7] + bl1;
      *(float2*)&out[(size_t)(t-1)*512 + wid*2] = make_float2(y0, y1);
      u32x4 rec;
      rec.x = __float_as_uint(y0); rec.y = __float_as_uint(y1);
      rec.z = (unsigned)t; rec.w = 0u;
      st16(ry + pcur*256 + wid, rec);
    }

    // ---- gates1 dot: regs j=0..5 (feat|h1) + LDS k=0..3 (WCL @ h2) ----
    float acc0 = 0.f, acc1 = 0.f;
    #pragma unroll
    for (int j = 0; j < 6; j++){
      float4 xv = *(float4*)&s_in[256*j + l*4];
      acc0 += DOT4(wA0[j], xv); acc1 += DOT4(wA1[j], xv);
    }
    #pragma unroll
    for (int k = 0; k < 4; k++){
      float4 xv = *(float4*)&s_in[1536 + 256*k + l*4];
      float4 u0 = *(float4*)&wa[o0*1024 + 256*k + l*4];
      float4 u1 = *(float4*)&wa[o1*1024 + 256*k + l*4];
      acc0 += DOT4(u0, xv); acc1 += DOT4(u1, xv);
    }
    #pragma unroll
    for (int mk = 32; mk; mk >>= 1){
      acc0 += __shfl_xor(acc0, mk); acc1 += __shfl_xor(acc1, mk);
    }
    if (l == 0){ s_part[o0] = acc0; s_part[o1] = acc1; }

    // ---- pB: precompute B's h2-dependent half (h2 in s_in[1536..2560)) ----
    float pB0, pB1;
    {
      float4 xv = *(float4*)&s_in[1536 + l*4];
      pB0 = DOT4(wB0[4], xv); pB1 = DOT4(wB1[4], xv);
      #pragma unroll
      for (int k = 0; k < 3; k++){
        float4 x2 = *(float4*)&s_in[1536 + 256 + 256*k + l*4];
        float4 u0 = *(float4*)&wb[o0*768 + 256*k + l*4];
        float4 u1 = *(float4*)&wb[o1*768 + 256*k + l*4];
        pB0 += DOT4(u0, x2); pB1 += DOT4(u1, x2);
      }
    }
    __syncthreads();

    // ---- finalize A (wave0): redundant lse from fused y records ----
    if (w == 0){
      float lse = 0.f;
      if (t > 0){
        const u32x4* pyr = ry + pcur*256 + 4*l;
        u32x4 r0, r1, r2, r3;
        for(;;){
          r0 = ld16(pyr); r1 = ld16(pyr+1); r2 = ld16(pyr+2); r3 = ld16(pyr+3);
          if (r0.z >= (unsigned)t && r1.z >= (unsigned)t &&
              r2.z >= (unsigned)t && r3.z >= (unsigned)t) break;
          __builtin_amdgcn_s_sleep(1);
        }
        float v0 = __uint_as_float(r0.x), v1 = __uint_as_float(r0.y);
        float v2 = __uint_as_float(r1.x), v3 = __uint_as_float(r1.y);
        float v4 = __uint_as_float(r2.x), v5 = __uint_as_float(r2.y);
        float v6 = __uint_as_float(r3.x), v7 = __uint_as_float(r3.y);
        float m0 = fmaxf(fmaxf(fmaxf(v0,v1), fmaxf(v2,v3)),
                         fmaxf(fmaxf(v4,v5), fmaxf(v6,v7)));
        #pragma unroll
        for (int mk = 32; mk; mk >>= 1) m0 = fmaxf(m0, __shfl_xor(m0, mk));
        float s = expf(v0-m0)+expf(v1-m0)+expf(v2-m0)+expf(v3-m0)
                + expf(v4-m0)+expf(v5-m0)+expf(v6-m0)+expf(v7-m0);
        #pragma unroll
        for (int mk = 32; mk; mk >>= 1) s += __shfl_xor(s, mk);
        lse = m0 + logf(s);
      }
      float hn = 0.f;
      if (l < 16){
        float sum = s_part[l] + biasAreg;
        if (t > 0) sum += bE2reg - rsReg*lse;
        float gi = __shfl(sum, (l & 3));
        float gf = __shfl(sum, 4 + (l & 3));
        float gg = __shfl(sum, 8 + (l & 3));
        float go = __shfl(sum, 12 + (l & 3));
        if (l < 4){
          float cn = sigm(gf)*c1 + sigm(gi)*tanhf(gg);
          c1 = cn;
          hn = sigm(go)*tanhf(cn);
        }
      }
      float g0 = __shfl(hn, 2*(l & 1));
      float g1 = __shfl(hn, 2*(l & 1) + 1);
      if (l < 2){
        u32x4 rec;
        rec.x = __float_as_uint(g0); rec.y = __float_as_uint(g1);
        rec.z = (unsigned)(t + 1); rec.w = 0u;
        st16(rh1 + pcur*512 + wid*2 + l, rec);
      }
    }

    // ---- phase B: h1(t) via fused records -> s_in[0..1024) ----
    {
      const u32x4* p1 = rh1 + pcur*512 + tid;
      u32x4 a;
      for(;;){
        a = ld16(p1);
        if (a.z >= (unsigned)(t + 1)) break;
        __builtin_amdgcn_s_sleep(1);
      }
      s_in[2*tid]     = __uint_as_float(a.x);
      s_in[2*tid + 1] = __uint_as_float(a.y);
    }
    __syncthreads();

    // ---- gates2 dot: regs j=0..3 (h1) + precomputed pB (h2 half) ----
    float b0 = pB0, b1 = pB1;
    #pragma unroll
    for (int j = 0; j < 4; j++){
      float4 xv = *(float4*)&s_in[256*j + l*4];
      b0 += DOT4(wB0[j], xv); b1 += DOT4(wB1[j], xv);
    }
    #pragma unroll
    for (int mk = 32; mk; mk >>= 1){
      b0 += __shfl_xor(b0, mk); b1 += __shfl_xor(b1, mk);
    }
    if (l == 0){ s_part[o0] = b0; s_part[o1] = b1; }
    __syncthreads();
    if (w == 0){
      float hn = 0.f;
      if (l < 16){
        float sum = s_part[l] + biasBreg;
        float gi = __shfl(sum, (l & 3));
        float gf = __shfl(sum, 4 + (l & 3));
        float gg = __shfl(sum, 8 + (l & 3));
        float go = __shfl(sum, 12 + (l & 3));
        if (l < 4){
          float cn = sigm(gf)*c2 + sigm(gi)*tanhf(gg);
          c2 = cn;
          hn = sigm(go)*tanhf(cn);
        }
      }
      float g0 = __shfl(hn, 2*(l & 1));
      float g1 = __shfl(hn, 2*(l & 1) + 1);
      if (l < 2){
        u32x4 rec;
        rec.x = __float_as_uint(g0); rec.y = __float_as_uint(g1);
        rec.z = (unsigned)(t + 1); rec.w = 0u;
        st16(rh2 + pcur*512 + wid*2 + l, rec);
      }
    }
  }

  // ===== tail: y(T-1) from RH2[(T-1)&1] records =====
  {
    const u32x4* p2 = rh2 + ((T_STEPS - 1) & 1)*512 + tid;
    u32x4 b;
    for(;;){
      b = ld16(p2);
      if (b.z >= (unsigned)T_STEPS) break;
      __builtin_amdgcn_s_sleep(1);
    }
    s_in[1536 + 2*tid]     = __uint_as_float(b.x);
    s_in[1536 + 2*tid + 1] = __uint_as_float(b.y);
  }
  __syncthreads();
  {
    int yrow = w >> 2, cb = (w & 3)*256 + l*4;
    float4 xv = *(float4*)&s_in[1536 + cb];
    float4 wv = *(float4*)&wy[yrow*1024 + cb];
    float yp = DOT4(wv, xv);
    #pragma unroll
    for (int mk = 32; mk; mk >>= 1) yp += __shfl_xor(yp, mk);
    if (l == 0) s_py[w] = yp;
  }
  __syncthreads();
  if (w == 0 && l == 0){
    out[(T_STEPS-1)*512 + wid*2    ] = s_py[0]+s_py[1]+s_py[2]+s_py[3] + bl0;
    out[(T_STEPS-1)*512 + wid*2 + 1] = s_py[4]+s_py[5]+s_py[6]+s_py[7] + bl1;
  }
}

// ---------------------------------------------------------------------------
extern "C" void kernel_launch(void* const* d_in, const int* in_sizes, int n_in,
                              void* d_out, int out_size, void* d_ws, size_t ws_size,
                              hipStream_t stream)
{
  const float* x    = (const float*)d_in[0];
  const float* Ws   = (const float*)d_in[1];
  const float* bs   = (const float*)d_in[2];
  const float* Wih1 = (const float*)d_in[3];
  const float* Whh1 = (const float*)d_in[4];
  const float* bih1 = (const float*)d_in[5];
  const float* bhh1 = (const float*)d_in[6];
  const float* Wih2 = (const float*)d_in[7];
  const float* Whh2 = (const float*)d_in[8];
  const float* bih2 = (const float*)d_in[9];
  const float* bhh2 = (const float*)d_in[10];
  const float* Wl   = (const float*)d_in[11];
  const float* bl   = (const float*)d_in[12];
  const float* Wm   = (const float*)d_in[13];
  const float* bm   = (const float*)d_in[14];
  char* wsb  = (char*)d_ws;
  float* out = (float*)d_out;

  // zero records (seq=0 < any need) -- fresh each call / graph replay
  hipMemsetAsync(wsb, 0, WS_ZERO_BYTES, stream);

  feat_kernel<<<256, 512, 0, stream>>>(x, Ws, bs, (float*)(wsb + WS_FEAT));
  lstm_persist<<<NWG, 512, SMEM_BYTES, stream>>>(
      Wih1, Whh1, Wih2, Whh2, Wl, Wm,
      bih1, bhh1, bih2, bhh2, bl, bm, wsb, out);
  ls_kernel<<<T_STEPS, 64, 0, stream>>>(out);
}

// Round 11
// 25113.643 us; speedup vs baseline: 2.2698x; 1.1821x over previous
//
#include <hip/hip_runtime.h>
#include <math.h>

// ---------------------------------------------------------------------------
// LSTM_FEAT_2: T=4096 sequential 2-layer LSTM + log-softmax feedback.
// R11: R10's fused data+seq 16B record protocol, restructured step:
//  - persistent LDS layout feat|h1|h2: B stages h1 where A reads it ->
//    A's rh1 poll DELETED (data already on-chip);
//  - partial gates1 (feat+h1, no h2 dependency) computed BEFORE the rh2
//    poll -> hides record visibility latency under compute;
//  - batched poll loads (ld16x4: 4 loads + ONE waitcnt; R10's ld16 embedded
//    vmcnt(0) per load = 4 serialized RTs in the lse poll);
//  - y(t-1) on wave0 alone (overlapped with other waves' WCL dots), one
//    fewer __syncthreads.
//
// Math (unchanged, verified R7-R10):
//   feat_t = Ws@x_t + bs                       (startup kernel)
//   gates1 = [Wih1s|Whh1]@[feat;h1] + WCL@h2 + biasA [+ biasE2 - rsWC*lse]
//     WCL=(Wih1e@Wm)@Wl, biasE2=Wih1e@bm+WC@bl, rsWC=rowsum(WC)
//   gates2 = [Wih2|Whh2]@[h1;h2] + biasB
//   y_t    = Wl@h2_t + bl -> d_out ; post-pass: out = log_softmax(out)
// ---------------------------------------------------------------------------

#define T_STEPS 4096
#define NWG 256

typedef unsigned u32x4 __attribute__((ext_vector_type(4)));

// ws layout (bytes)
#define WS_RH1   0            // u32x4[2][512]: h1 records {h,h,seq,0} (16KB)
#define WS_RH2   16384        // u32x4[2][512]: h2 records (16KB)
#define WS_RY    32768        // u32x4[2][256]: y  records {y0,y1,seq,0} (8KB)
#define WS_ZERO_BYTES 40960
#define WS_FEAT  40960        // float[4096][512] -> end ~8.4MB

// dynamic LDS partition (floats)
#define OFF_WA 2560           // s_in[2560] | wa[16][1024] | wb[16][768] | wy[2][1024]
#define OFF_WB 18944
#define OFF_WY 31232
#define SMEM_FLOATS 33280
#define SMEM_BYTES  (SMEM_FLOATS*4)

#define PIN4(v) asm volatile("" : "+v"((v).x), "+v"((v).y), "+v"((v).z), "+v"((v).w))
#define PIN1(v) asm volatile("" : "+v"(v))
#define FMA4(acc,s,v4) {(acc).x += (s)*(v4).x; (acc).y += (s)*(v4).y; (acc).z += (s)*(v4).z; (acc).w += (s)*(v4).w;}
#define DOT4(a,b) ((a).x*(b).x + (a).y*(b).y + (a).z*(b).z + (a).w*(b).w)

// coherent 16B transactional load/store (bypass L1/L2 -> LLC)
__device__ __forceinline__ u32x4 ld16(const u32x4* p){
  u32x4 r;
  asm volatile("global_load_dwordx4 %0, %1, off sc0 sc1\n\ts_waitcnt vmcnt(0)"
               : "=v"(r) : "v"(p) : "memory");
  return r;
}
// 4 contiguous records, ONE waitcnt (offset immediates)
__device__ __forceinline__ void ld16x4(const u32x4* p, u32x4& r0, u32x4& r1,
                                       u32x4& r2, u32x4& r3){
  asm volatile("global_load_dwordx4 %0, %4, off sc0 sc1\n\t"
               "global_load_dwordx4 %1, %4, off offset:16 sc0 sc1\n\t"
               "global_load_dwordx4 %2, %4, off offset:32 sc0 sc1\n\t"
               "global_load_dwordx4 %3, %4, off offset:48 sc0 sc1\n\t"
               "s_waitcnt vmcnt(0)"
               : "=&v"(r0), "=&v"(r1), "=&v"(r2), "=&v"(r3)
               : "v"(p) : "memory");
}
__device__ __forceinline__ void st16(u32x4* p, u32x4 v){
  asm volatile("global_store_dwordx4 %0, %1, off sc0 sc1"
               :: "v"(p), "v"(v) : "memory");
}
__device__ __forceinline__ float sigm(float x){ return 1.0f/(1.0f+expf(-x)); }

// ---------------------------------------------------------------------------
// startup: feat[t][k] = Ws[k]·x[t] + bs[k]
__global__ __launch_bounds__(512) void feat_kernel(
    const float* __restrict__ x, const float* __restrict__ Ws,
    const float* __restrict__ bs, float* __restrict__ feat)
{
  __shared__ float s_x[16][360];
  __shared__ float s_w[512][20];
  const int bid = blockIdx.x, tid = threadIdx.x;
  const int t0 = bid * 16;
  for (int tt = 0; tt < 16; tt++)
    if (tid < 360) s_x[tt][tid] = x[(t0+tt)*360 + tid];
  float acc[16];
  #pragma unroll
  for (int i = 0; i < 16; i++) acc[i] = 0.f;
  for (int d0 = 0; d0 < 360; d0 += 16){
    const int dn = (360 - d0 < 16) ? (360 - d0) : 16;
    __syncthreads();
    if (dn == 16){
      #pragma unroll
      for (int c4 = 0; c4 < 4; c4++)
        *(float4*)&s_w[tid][c4*4] = *(const float4*)&Ws[tid*360 + d0 + c4*4];
    } else {
      for (int c = 0; c < dn; c++) s_w[tid][c] = Ws[tid*360 + d0 + c];
    }
    __syncthreads();
    for (int c = 0; c < dn; c++){
      float wv = s_w[tid][c];
      #pragma unroll
      for (int tt = 0; tt < 16; tt++) acc[tt] += wv * s_x[tt][d0 + c];
    }
  }
  for (int tt = 0; tt < 16; tt++)
    feat[(t0+tt)*512 + tid] = acc[tt] + bs[tid];
}

// ---------------------------------------------------------------------------
// post-pass: out[t] = out[t] - logsumexp(out[t])  (in place)
__global__ __launch_bounds__(64) void ls_kernel(float* __restrict__ out)
{
  const int t = blockIdx.x, l = threadIdx.x;
  float v[8];
  #pragma unroll
  for (int i = 0; i < 8; i++) v[i] = out[t*512 + l*8 + i];
  float m0 = v[0];
  #pragma unroll
  for (int i = 1; i < 8; i++) m0 = fmaxf(m0, v[i]);
  #pragma unroll
  for (int mk = 32; mk; mk >>= 1) m0 = fmaxf(m0, __shfl_xor(m0, mk));
  float s = 0.f;
  #pragma unroll
  for (int i = 0; i < 8; i++) s += expf(v[i] - m0);
  #pragma unroll
  for (int mk = 32; mk; mk >>= 1) s += __shfl_xor(s, mk);
  float lse = m0 + logf(s);
  #pragma unroll
  for (int i = 0; i < 8; i++) out[t*512 + l*8 + i] = v[i] - lse;
}

// ---------------------------------------------------------------------------
// persistent kernel: 256 wgs x 512 thr (8 waves), 1 wg/CU via 133KB LDS.
// Wave w owns gate rows {2w,2w+1}; lane l owns f4 col-chunks (bank-clean).
// s_in layout (persistent): feat[0,512) | h1[512,1536) | h2[1536,2560).
__global__ __launch_bounds__(512, 1) void lstm_persist(
    const float* __restrict__ Wih1, const float* __restrict__ Whh1,
    const float* __restrict__ Wih2, const float* __restrict__ Whh2,
    const float* __restrict__ Wl,   const float* __restrict__ Wm,
    const float* __restrict__ bih1, const float* __restrict__ bhh1,
    const float* __restrict__ bih2, const float* __restrict__ bhh2,
    const float* __restrict__ blp,  const float* __restrict__ bmp,
    char* __restrict__ wsb, float* __restrict__ out)
{
  extern __shared__ float smem[];
  float* s_in = smem;               // feat | h1 | h2 (persistent regions)
  float* wa   = smem + OFF_WA;      // [16][1024] = WCL rows
  float* wb   = smem + OFF_WB;      // [16][768]  = Whh2 cols 256..1023 (init: WCtmp)
  float* wy   = smem + OFF_WY;      // [2][1024]  = Wl rows wid*2, wid*2+1
  __shared__ float s_part[16];
  __shared__ float s_sums[32];

  u32x4* rh1 = (u32x4*)(wsb + WS_RH1);   // [2][512]
  u32x4* rh2 = (u32x4*)(wsb + WS_RH2);   // [2][512]
  u32x4* ry  = (u32x4*)(wsb + WS_RY);    // [2][256]
  const float* featp = (const float*)(wsb + WS_FEAT);

  const int wid = blockIdx.x, tid = threadIdx.x;
  const int w = tid >> 6, l = tid & 63;
  const int o0 = 2*w, o1 = 2*w + 1;
  const int rA0 = (o0 >> 2)*1024 + wid*4 + (o0 & 3);
  const int rA1 = (o1 >> 2)*1024 + wid*4 + (o1 & 3);

  // ===== init 1: stage this wg's 16 Wih1e rows (16x128) into s_in =====
  for (int idx = tid; idx < 2048; idx += 512){
    int o = idx >> 7, e = idx & 127;
    int r = (o >> 2)*1024 + wid*4 + (o & 3);
    s_in[idx] = Wih1[r*640 + 512 + e];
  }
  __syncthreads();

  // ===== init 2: WCtmp = Wih1e @ Wm  (16x512) -> wb area =====
  {
    float4 a00 = {0,0,0,0}, a01 = a00, a10 = a00, a11 = a00;
    for (int e = 0; e < 128; e++){
      float w0e = s_in[o0*128 + e], w1e = s_in[o1*128 + e];
      float4 m0 = *(const float4*)&Wm[e*512 + l*4];
      float4 m1 = *(const float4*)&Wm[e*512 + l*4 + 256];
      FMA4(a00, w0e, m0); FMA4(a01, w0e, m1);
      FMA4(a10, w1e, m0); FMA4(a11, w1e, m1);
    }
    *(float4*)&wb[o0*512 + l*4]       = a00;
    *(float4*)&wb[o0*512 + l*4 + 256] = a01;
    *(float4*)&wb[o1*512 + l*4]       = a10;
    *(float4*)&wb[o1*512 + l*4 + 256] = a11;
  }
  __syncthreads();

  // ===== init 3: WCL = WCtmp @ Wl (16x1024) -> wa; rowsum/bl piggyback =====
  {
    float4 c00={0,0,0,0}, c01=c00, c02=c00, c03=c00;
    float4 c10=c00, c11=c00, c12=c00, c13=c00;
    float rs0=0.f, rs1=0.f, wl0=0.f, wl1=0.f;
    for (int m = 0; m < 512; m++){
      float t0 = wb[o0*512 + m], t1 = wb[o1*512 + m];
      float blm = blp[m];
      rs0 += t0; wl0 += t0*blm; rs1 += t1; wl1 += t1*blm;
      float4 q0 = *(const float4*)&Wl[m*1024 + l*4];
      float4 q1 = *(const float4*)&Wl[m*1024 + l*4 + 256];
      float4 q2 = *(const float4*)&Wl[m*1024 + l*4 + 512];
      float4 q3 = *(const float4*)&Wl[m*1024 + l*4 + 768];
      FMA4(c00,t0,q0); FMA4(c01,t0,q1); FMA4(c02,t0,q2); FMA4(c03,t0,q3);
      FMA4(c10,t1,q0); FMA4(c11,t1,q1); FMA4(c12,t1,q2); FMA4(c13,t1,q3);
    }
    *(float4*)&wa[o0*1024 + l*4      ] = c00;
    *(float4*)&wa[o0*1024 + l*4 + 256] = c01;
    *(float4*)&wa[o0*1024 + l*4 + 512] = c02;
    *(float4*)&wa[o0*1024 + l*4 + 768] = c03;
    *(float4*)&wa[o1*1024 + l*4      ] = c10;
    *(float4*)&wa[o1*1024 + l*4 + 256] = c11;
    *(float4*)&wa[o1*1024 + l*4 + 512] = c12;
    *(float4*)&wa[o1*1024 + l*4 + 768] = c13;
    if (l == 0){
      s_sums[w*4+0] = rs0; s_sums[w*4+1] = rs1;
      s_sums[w*4+2] = wl0; s_sums[w*4+3] = wl1;
    }
  }
  __syncthreads();

  // ===== init 4: per-row bias regs (wave 0) =====
  float biasAreg=0.f, biasBreg=0.f, bE2reg=0.f, rsReg=0.f;
  float bl0=0.f, bl1=0.f, c1=0.f, c2=0.f;
  if (w == 0 && l < 16){
    int r = (l >> 2)*1024 + wid*4 + (l & 3);
    biasAreg = bih1[r] + bhh1[r];
    biasBreg = bih2[r] + bhh2[r];
    rsReg = s_sums[(l>>1)*4 + (l&1)];
    float acc = s_sums[(l>>1)*4 + 2 + (l&1)];
    for (int e = 0; e < 128; e++) acc += s_in[l*128 + e] * bmp[e];
    bE2reg = acc;
  }
  if (w == 0 && l == 0){ bl0 = blp[wid*2]; bl1 = blp[wid*2 + 1]; }
  __syncthreads();     // init4's s_in reads done before zeroing below

  // ===== init 5: zero h1/h2 regions; LDS weights wb (Whh2) and wy (Wl) ====
  for (int idx = tid; idx < 2048; idx += 512) s_in[512 + idx] = 0.f;
  for (int o = 0; o < 16; o++){
    int r = (o >> 2)*1024 + wid*4 + (o & 3);
    for (int c = tid; c < 768; c += 512)
      wb[o*768 + c] = Whh2[r*1024 + 256 + c];
  }
  for (int idx = tid; idx < 2048; idx += 512){
    int row = idx >> 10, c = idx & 1023;
    wy[idx] = Wl[(wid*2 + row)*1024 + c];
  }

  // ===== init 6: pinned register weights (88 floats/thread) =====
  float4 wA0[6], wA1[6], wB0[5], wB1[5];
  #pragma unroll
  for (int j = 0; j < 6; j++){
    int c = 256*j + l*4;
    wA0[j] = (c < 512) ? *(const float4*)&Wih1[rA0*640 + c]
                       : *(const float4*)&Whh1[rA0*1024 + c - 512];
    wA1[j] = (c < 512) ? *(const float4*)&Wih1[rA1*640 + c]
                       : *(const float4*)&Whh1[rA1*1024 + c - 512];
  }
  #pragma unroll
  for (int j = 0; j < 5; j++){
    int c = 256*j + l*4;
    wB0[j] = (c < 1024) ? *(const float4*)&Wih2[rA0*1024 + c]
                        : *(const float4*)&Whh2[rA0*1024 + c - 1024];
    wB1[j] = (c < 1024) ? *(const float4*)&Wih2[rA1*1024 + c]
                        : *(const float4*)&Whh2[rA1*1024 + c - 1024];
  }
  #pragma unroll
  for (int j = 0; j < 6; j++){ PIN4(wA0[j]); PIN4(wA1[j]); }
  #pragma unroll
  for (int j = 0; j < 5; j++){ PIN4(wB0[j]); PIN4(wB1[j]); }
  PIN1(biasAreg); PIN1(biasBreg); PIN1(bE2reg); PIN1(rsReg);
  PIN1(bl0); PIN1(bl1);
  __syncthreads();

  // ===== main loop =====
  for (int t = 0; t < T_STEPS; t++){
    const int pprev = (t + 1) & 1;       // parity of step t-1
    const int pcur  = t & 1;             // parity of step t

    // ---- A1: stage feat(t) (h1(t-1) already in s_in[512,1536) from B) ----
    if (tid < 256)
      *(float2*)&s_in[tid*2] = *(const float2*)&featp[(size_t)t*512 + tid*2];
    __syncthreads();

    // ---- A2: partial gates1 (feat+h1 cols, reg weights) -- NO h2 dep ----
    float acc0 = 0.f, acc1 = 0.f;
    #pragma unroll
    for (int j = 0; j < 6; j++){
      float4 xv = *(float4*)&s_in[256*j + l*4];
      acc0 += DOT4(wA0[j], xv); acc1 += DOT4(wA1[j], xv);
    }

    // ---- A3: poll h2(t-1) record (hidden partly under A2's flight) ----
    if (t > 0){
      const u32x4* p2 = rh2 + pprev*512 + tid;
      u32x4 b;
      for(;;){
        b = ld16(p2);
        if (b.z >= (unsigned)t) break;
        __builtin_amdgcn_s_sleep(1);
      }
      *(float2*)&s_in[1536 + 2*tid] =
          make_float2(__uint_as_float(b.x), __uint_as_float(b.y));
    }
    __syncthreads();

    // ---- A4: wave0: y(t-1) full dot + publish; all: WCL dot + pB ----
    if (t > 0 && w == 0){
      float y0 = 0.f, y1 = 0.f;
      #pragma unroll
      for (int i = 0; i < 4; i++){
        float4 xv = *(float4*)&s_in[1536 + 256*i + l*4];
        float4 w0 = *(float4*)&wy[256*i + l*4];
        float4 w1 = *(float4*)&wy[1024 + 256*i + l*4];
        y0 += DOT4(w0, xv); y1 += DOT4(w1, xv);
      }
      #pragma unroll
      for (int mk = 32; mk; mk >>= 1){
        y0 += __shfl_xor(y0, mk); y1 += __shfl_xor(y1, mk);
      }
      if (l == 0){
        y0 += bl0; y1 += bl1;
        *(float2*)&out[(size_t)(t-1)*512 + wid*2] = make_float2(y0, y1);
        u32x4 rec;
        rec.x = __float_as_uint(y0); rec.y = __float_as_uint(y1);
        rec.z = (unsigned)t; rec.w = 0u;
        st16(ry + pcur*256 + wid, rec);
      }
    }
    #pragma unroll
    for (int k = 0; k < 4; k++){
      float4 xv = *(float4*)&s_in[1536 + 256*k + l*4];
      float4 u0 = *(float4*)&wa[o0*1024 + 256*k + l*4];
      float4 u1 = *(float4*)&wa[o1*1024 + 256*k + l*4];
      acc0 += DOT4(u0, xv); acc1 += DOT4(u1, xv);
    }
    #pragma unroll
    for (int mk = 32; mk; mk >>= 1){
      acc0 += __shfl_xor(acc0, mk); acc1 += __shfl_xor(acc1, mk);
    }
    if (l == 0){ s_part[o0] = acc0; s_part[o1] = acc1; }

    // pB: precompute gates2's h2-dependent half (h2 in s_in[1536,2560))
    float pB0, pB1;
    {
      float4 xv = *(float4*)&s_in[1536 + l*4];
      pB0 = DOT4(wB0[4], xv); pB1 = DOT4(wB1[4], xv);
      #pragma unroll
      for (int k = 0; k < 3; k++){
        float4 x2 = *(float4*)&s_in[1536 + 256 + 256*k + l*4];
        float4 u0 = *(float4*)&wb[o0*768 + 256*k + l*4];
        float4 u1 = *(float4*)&wb[o1*768 + 256*k + l*4];
        pB0 += DOT4(u0, x2); pB1 += DOT4(u1, x2);
      }
    }
    __syncthreads();

    // ---- A5: finalize (wave0): batched lse poll, gates, publish rh1 ----
    if (w == 0){
      float lse = 0.f;
      if (t > 0){
        const u32x4* pyr = ry + pcur*256 + 4*l;
        u32x4 r0, r1, r2, r3;
        for(;;){
          ld16x4(pyr, r0, r1, r2, r3);
          if (r0.z >= (unsigned)t && r1.z >= (unsigned)t &&
              r2.z >= (unsigned)t && r3.z >= (unsigned)t) break;
          __builtin_amdgcn_s_sleep(1);
        }
        float v0 = __uint_as_float(r0.x), v1 = __uint_as_float(r0.y);
        float v2 = __uint_as_float(r1.x), v3 = __uint_as_float(r1.y);
        float v4 = __uint_as_float(r2.x), v5 = __uint_as_float(r2.y);
        float v6 = __uint_as_float(r3.x), v7 = __uint_as_float(r3.y);
        float m0 = fmaxf(fmaxf(fmaxf(v0,v1), fmaxf(v2,v3)),
                         fmaxf(fmaxf(v4,v5), fmaxf(v6,v7)));
        #pragma unroll
        for (int mk = 32; mk; mk >>= 1) m0 = fmaxf(m0, __shfl_xor(m0, mk));
        float s = expf(v0-m0)+expf(v1-m0)+expf(v2-m0)+expf(v3-m0)
                + expf(v4-m0)+expf(v5-m0)+expf(v6-m0)+expf(v7-m0);
        #pragma unroll
        for (int mk = 32; mk; mk >>= 1) s += __shfl_xor(s, mk);
        lse = m0 + logf(s);
      }
      float hn = 0.f;
      if (l < 16){
        float sum = s_part[l] + biasAreg;
        if (t > 0) sum += bE2reg - rsReg*lse;
        float gi = __shfl(sum, (l & 3));
        float gf = __shfl(sum, 4 + (l & 3));
        float gg = __shfl(sum, 8 + (l & 3));
        float go = __shfl(sum, 12 + (l & 3));
        if (l < 4){
          float cn = sigm(gf)*c1 + sigm(gi)*tanhf(gg);
          c1 = cn;
          hn = sigm(go)*tanhf(cn);
        }
      }
      float g0 = __shfl(hn, 2*(l & 1));
      float g1 = __shfl(hn, 2*(l & 1) + 1);
      if (l < 2){
        u32x4 rec;
        rec.x = __float_as_uint(g0); rec.y = __float_as_uint(g1);
        rec.z = (unsigned)(t + 1); rec.w = 0u;
        st16(rh1 + pcur*512 + wid*2 + l, rec);
      }
    }

    // ---- B1: poll h1(t) records -> s_in[512,1536) ----
    {
      const u32x4* p1 = rh1 + pcur*512 + tid;
      u32x4 a;
      for(;;){
        a = ld16(p1);
        if (a.z >= (unsigned)(t + 1)) break;
        __builtin_amdgcn_s_sleep(1);
      }
      *(float2*)&s_in[512 + 2*tid] =
          make_float2(__uint_as_float(a.x), __uint_as_float(a.y));
    }
    __syncthreads();

    // ---- B2: gates2 dot: regs j=0..3 on h1 + precomputed pB ----
    float b0 = pB0, b1 = pB1;
    #pragma unroll
    for (int j = 0; j < 4; j++){
      float4 xv = *(float4*)&s_in[512 + 256*j + l*4];
      b0 += DOT4(wB0[j], xv); b1 += DOT4(wB1[j], xv);
    }
    #pragma unroll
    for (int mk = 32; mk; mk >>= 1){
      b0 += __shfl_xor(b0, mk); b1 += __shfl_xor(b1, mk);
    }
    if (l == 0){ s_part[o0] = b0; s_part[o1] = b1; }
    __syncthreads();

    // ---- B3: finalize (wave0), publish rh2 ----
    if (w == 0){
      float hn = 0.f;
      if (l < 16){
        float sum = s_part[l] + biasBreg;
        float gi = __shfl(sum, (l & 3));
        float gf = __shfl(sum, 4 + (l & 3));
        float gg = __shfl(sum, 8 + (l & 3));
        float go = __shfl(sum, 12 + (l & 3));
        if (l < 4){
          float cn = sigm(gf)*c2 + sigm(gi)*tanhf(gg);
          c2 = cn;
          hn = sigm(go)*tanhf(cn);
        }
      }
      float g0 = __shfl(hn, 2*(l & 1));
      float g1 = __shfl(hn, 2*(l & 1) + 1);
      if (l < 2){
        u32x4 rec;
        rec.x = __float_as_uint(g0); rec.y = __float_as_uint(g1);
        rec.z = (unsigned)(t + 1); rec.w = 0u;
        st16(rh2 + pcur*512 + wid*2 + l, rec);
      }
    }
  }

  // ===== tail: y(T-1) from rh2[(T-1)&1] records =====
  {
    const u32x4* p2 = rh2 + ((T_STEPS - 1) & 1)*512 + tid;
    u32x4 b;
    for(;;){
      b = ld16(p2);
      if (b.z >= (unsigned)T_STEPS) break;
      __builtin_amdgcn_s_sleep(1);
    }
    *(float2*)&s_in[1536 + 2*tid] =
        make_float2(__uint_as_float(b.x), __uint_as_float(b.y));
  }
  __syncthreads();
  if (w == 0){
    float y0 = 0.f, y1 = 0.f;
    #pragma unroll
    for (int i = 0; i < 4; i++){
      float4 xv = *(float4*)&s_in[1536 + 256*i + l*4];
      float4 w0 = *(float4*)&wy[256*i + l*4];
      float4 w1 = *(float4*)&wy[1024 + 256*i + l*4];
      y0 += DOT4(w0, xv); y1 += DOT4(w1, xv);
    }
    #pragma unroll
    for (int mk = 32; mk; mk >>= 1){
      y0 += __shfl_xor(y0, mk); y1 += __shfl_xor(y1, mk);
    }
    if (l == 0)
      *(float2*)&out[(size_t)(T_STEPS-1)*512 + wid*2] =
          make_float2(y0 + bl0, y1 + bl1);
  }
}

// ---------------------------------------------------------------------------
extern "C" void kernel_launch(void* const* d_in, const int* in_sizes, int n_in,
                              void* d_out, int out_size, void* d_ws, size_t ws_size,
                              hipStream_t stream)
{
  const float* x    = (const float*)d_in[0];
  const float* Ws   = (const float*)d_in[1];
  const float* bs   = (const float*)d_in[2];
  const float* Wih1 = (const float*)d_in[3];
  const float* Whh1 = (const float*)d_in[4];
  const float* bih1 = (const float*)d_in[5];
  const float* bhh1 = (const float*)d_in[6];
  const float* Wih2 = (const float*)d_in[7];
  const float* Whh2 = (const float*)d_in[8];
  const float* bih2 = (const float*)d_in[9];
  const float* bhh2 = (const float*)d_in[10];
  const float* Wl   = (const float*)d_in[11];
  const float* bl   = (const float*)d_in[12];
  const float* Wm   = (const float*)d_in[13];
  const float* bm   = (const float*)d_in[14];
  char* wsb  = (char*)d_ws;
  float* out = (float*)d_out;

  // zero records (seq=0 < any need) -- fresh each call / graph replay
  hipMemsetAsync(wsb, 0, WS_ZERO_BYTES, stream);

  feat_kernel<<<256, 512, 0, stream>>>(x, Ws, bs, (float*)(wsb + WS_FEAT));
  lstm_persist<<<NWG, 512, SMEM_BYTES, stream>>>(
      Wih1, Whh1, Wih2, Whh2, Wl, Wm,
      bih1, bhh1, bih2, bhh2, bl, bm, wsb, out);
  ls_kernel<<<T_STEPS, 64, 0, stream>>>(out);
}